// Round 11
// baseline (620.827 us; speedup 1.0000x reference)
//
#include <hip/hip_runtime.h>
#include <math.h>

#define NTOK 4096
#define NB 4
#define NH 16
#define HD 64
#define HID 1024
#define BH 64          // NB*NH
#define QSCALE 0.125f  // 64^-0.5

typedef unsigned short u16;
typedef unsigned int u32;
typedef __attribute__((ext_vector_type(8))) _Float16 f16x8;
typedef __attribute__((ext_vector_type(8))) short s16x8;
typedef __attribute__((ext_vector_type(4))) float f32x4;
#define MFMA_F16(a, b, c) __builtin_amdgcn_mfma_f32_16x16x32_f16(a, b, c, 0, 0, 0)
#define MFMA_BF16(a, b, c) __builtin_amdgcn_mfma_f32_16x16x32_bf16(a, b, c, 0, 0, 0)
// async global -> LDS, 16B per lane, dest = wave-uniform base + lane*16
#define GLDS16(gptr, lptr)                                                          \
  __builtin_amdgcn_global_load_lds(                                                \
      (const __attribute__((address_space(1))) void*)(gptr),                       \
      (__attribute__((address_space(3))) void*)(lptr), 16, 0, 0)
#define VMCNT0() asm volatile("s_waitcnt vmcnt(0)" ::: "memory")

__device__ __forceinline__ float bf2f(u32 u) {
  union { u32 i; float f; } x; x.i = u << 16; return x.f;
}
__device__ __forceinline__ u32 f2bf(float f) {
  union { float f; u32 i; } x; x.f = f;
  return (x.i + 0x7fffu + ((x.i >> 16) & 1u)) >> 16;  // RTNE
}
__device__ __forceinline__ u32 pk2(float a, float b) {
  return f2bf(a) | (f2bf(b) << 16);
}
__device__ __forceinline__ u32 pkh2(float a, float b) {  // 2 x f32 -> packed fp16
  _Float16 ha = (_Float16)a, hb = (_Float16)b;
  u16 x, y;
  __builtin_memcpy(&x, &ha, 2);
  __builtin_memcpy(&y, &hb, 2);
  return (u32)x | ((u32)y << 16);
}
__device__ __forceinline__ u16 f2h(float a) {
  _Float16 h = (_Float16)a;
  u16 x;
  __builtin_memcpy(&x, &h, 2);
  return x;
}
__device__ __forceinline__ void up8(uint4 a, float* f) {  // 8 bf16 -> f32
  f[0] = bf2f(a.x & 0xffffu); f[1] = bf2f(a.x >> 16);
  f[2] = bf2f(a.y & 0xffffu); f[3] = bf2f(a.y >> 16);
  f[4] = bf2f(a.z & 0xffffu); f[5] = bf2f(a.z >> 16);
  f[6] = bf2f(a.w & 0xffffu); f[7] = bf2f(a.w >> 16);
}
__device__ __forceinline__ void up8h(uint4 a, float* f) {  // 8 fp16 -> f32
  union { uint4 u; _Float16 h[8]; } x;
  x.u = a;
#pragma unroll
  for (int c = 0; c < 8; ++c) f[c] = (float)x.h[c];
}

// ---------------- diagnostic fill ----------------
__global__ void fill_kernel(float* __restrict__ out, int n, float v) {
  int i = blockIdx.x * 256 + threadIdx.x;
  if (i < n) out[i] = v;
}

// ---------------- RoPE tables ----------------
__global__ void rope_table_kernel(float* __restrict__ ct, float* __restrict__ st) {
  int idx = blockIdx.x * 256 + threadIdx.x;
  if (idx >= NTOK * 32) return;
  int n = idx >> 5, i = idx & 31;
  float t = powf(10000.0f, (float)(2 * i));   // inf for i>=5 -> inv=0 (matches f64 ~1e-245)
  float inv = 1.0f / (t / 64.0f);
  float f = (float)n * inv;
  ct[idx] = cosf(f);
  st[idx] = sinf(f);
}

// ---------------- LayerNorm -> fp16 ----------------
__global__ __launch_bounds__(256) void ln_f16_kernel(const float* __restrict__ in,
                                                     const float* __restrict__ gm,
                                                     const float* __restrict__ bt,
                                                     u16* __restrict__ out) {
  __shared__ float sh[8];
  int row = blockIdx.x, t = threadIdx.x;
  float4 x = ((const float4*)(in + (size_t)row * HID))[t];
  float s1 = x.x + x.y + x.z + x.w;
  float s2 = x.x * x.x + x.y * x.y + x.z * x.z + x.w * x.w;
#pragma unroll
  for (int o = 32; o > 0; o >>= 1) {
    s1 += __shfl_down(s1, o, 64);
    s2 += __shfl_down(s2, o, 64);
  }
  if ((t & 63) == 0) { sh[t >> 6] = s1; sh[4 + (t >> 6)] = s2; }
  __syncthreads();
  float S1 = sh[0] + sh[1] + sh[2] + sh[3];
  float S2 = sh[4] + sh[5] + sh[6] + sh[7];
  float mu = S1 * (1.0f / HID);
  float var = S2 * (1.0f / HID) - mu * mu;
  float rstd = 1.0f / sqrtf(var + 1e-5f);
  float4 g = ((const float4*)gm)[t], b = ((const float4*)bt)[t];
  float o0 = (x.x - mu) * rstd * g.x + b.x;
  float o1 = (x.y - mu) * rstd * g.y + b.y;
  float o2 = (x.z - mu) * rstd * g.z + b.z;
  float o3 = (x.w - mu) * rstd * g.w + b.w;
  *(uint2*)&out[(size_t)row * HID + t * 4] = make_uint2(pkh2(o0, o1), pkh2(o2, o3));
}

// ---------------- weight prep: w [1024][N] f32 -> w^T fp16 [N][1024] ----------------
__global__ __launch_bounds__(256) void prep_w_kernel(const float* __restrict__ w,
                                                     u16* __restrict__ wt, int N) {
  __shared__ float T[64][65];
  int t = threadIdx.x;
  int n0 = blockIdx.x * 64, k0 = blockIdx.y * 64;
  {
    int k = t >> 2, nc = (t & 3) * 16;
    const float* src = w + (size_t)(k0 + k) * N + n0 + nc;
#pragma unroll
    for (int i = 0; i < 4; ++i) {
      float4 x = *(const float4*)(src + i * 4);
      T[nc + i * 4 + 0][k] = x.x;
      T[nc + i * 4 + 1][k] = x.y;
      T[nc + i * 4 + 2][k] = x.z;
      T[nc + i * 4 + 3][k] = x.w;
    }
  }
  __syncthreads();
  {
    int n = t >> 2, kc = (t & 3) * 16;
    u32 pk[8];
#pragma unroll
    for (int j = 0; j < 8; ++j) pk[j] = pkh2(T[n][kc + 2 * j], T[n][kc + 2 * j + 1]);
    size_t dst = (size_t)(n0 + n) * 1024 + k0 + kc;
    *(uint4*)&wt[dst] = make_uint4(pk[0], pk[1], pk[2], pk[3]);
    *(uint4*)&wt[dst + 8] = make_uint4(pk[4], pk[5], pk[6], pk[7]);
  }
}

// ---------------- fp16 MFMA GEMM, 128x128 tile, BK=32, 4 waves ----------------
// T3 minimum 2-phase pipeline: double-buffered LDS, issue next-tile global_load_lds
// BEFORE computing current tile, one raw s_barrier + vmcnt(0) per K-step.
template <int MODE>
__global__ __launch_bounds__(256) void gemm_f16_kernel(
    const u16* __restrict__ At, const u16* __restrict__ Bt,
    u16* __restrict__ qd, u16* __restrict__ kd, u16* __restrict__ vd,
    const float* __restrict__ ct, const float* __restrict__ st,
    const float* __restrict__ bias, float* __restrict__ C) {
  __shared__ __align__(16) u16 As[2][128 * 32], Bs[2][128 * 32];
  const int t = threadIdx.x;
  const int m0 = blockIdx.y * 128, n0 = blockIdx.x * 128;
  const int l = t & 63, w = t >> 6;
  const int wm = w & 1, wn = w >> 1;
  const int lr = l & 15, kg = (l >> 4) * 8;

  // staging: wave w covers rows [32w, 32w+32); lane l -> row +(l>>2), 16B chunk (l&3)
  const u16* gA = At + (size_t)(m0 + w * 32 + (l >> 2)) * 1024 + (l & 3) * 8;
  const u16* gB = Bt + (size_t)(n0 + w * 32 + (l >> 2)) * 1024 + (l & 3) * 8;
  const int wbase = (w * 32) * 32;  // wave-uniform LDS base offset (u16 units)

  f32x4 zero4 = {0.f, 0.f, 0.f, 0.f};
  f32x4 acc[4][4];
#pragma unroll
  for (int mf = 0; mf < 4; ++mf)
#pragma unroll
    for (int nf = 0; nf < 4; ++nf) acc[mf][nf] = zero4;

  // prologue: stage K-tile 0 into buffer 0
  GLDS16(gA, &As[0][wbase]);
  GLDS16(gA + (size_t)16 * 1024, &As[0][wbase + 16 * 32]);
  GLDS16(gB, &Bs[0][wbase]);
  GLDS16(gB + (size_t)16 * 1024, &Bs[0][wbase + 16 * 32]);
  VMCNT0();
  __builtin_amdgcn_s_barrier();

  for (int k0 = 0; k0 < 1024; k0 += 32) {
    const int cur = (k0 >> 5) & 1;
    if (k0 + 32 < 1024) {  // issue next-tile loads first (latency hides under MFMA)
      const int nxt = cur ^ 1;
      GLDS16(gA + k0 + 32, &As[nxt][wbase]);
      GLDS16(gA + k0 + 32 + (size_t)16 * 1024, &As[nxt][wbase + 16 * 32]);
      GLDS16(gB + k0 + 32, &Bs[nxt][wbase]);
      GLDS16(gB + k0 + 32 + (size_t)16 * 1024, &Bs[nxt][wbase + 16 * 32]);
    }
    f16x8 af[4];
#pragma unroll
    for (int mf = 0; mf < 4; ++mf)
      af[mf] = *(const f16x8*)&As[cur][(wm * 64 + mf * 16 + lr) * 32 + kg];
#pragma unroll
    for (int nf = 0; nf < 4; ++nf) {
      f16x8 bf = *(const f16x8*)&Bs[cur][(wn * 64 + nf * 16 + lr) * 32 + kg];
#pragma unroll
      for (int mf = 0; mf < 4; ++mf) acc[mf][nf] = MFMA_F16(af[mf], bf, acc[mf][nf]);
    }
    // drain this step's prefetch, then barrier: next buffer ready, and all waves'
    // ds_reads of buf[cur] completed (they precede each wave's arrival here).
    VMCNT0();
    __builtin_amdgcn_s_barrier();
  }

  if (MODE == 0) {
#pragma unroll
    for (int nf = 0; nf < 4; ++nf) {
      int col = n0 + wn * 64 + nf * 16 + (l & 15);
      int which = col >> 10;            // wave-uniform: 0:q 1:k 2:v
      int rem = col & 1023;
      int h = rem >> 6, d = rem & 63;
      int fi = d >> 1;
      float sc = (which == 0) ? QSCALE : 1.0f;
#pragma unroll
      for (int mf = 0; mf < 4; ++mf) {
#pragma unroll
        for (int r = 0; r < 4; ++r) {
          int row = m0 + wm * 64 + mf * 16 + (l >> 4) * 4 + r;
          int bbo = row >> 12, n = row & 4095;
          size_t idx = ((size_t)(bbo * NH + h) * NTOK + n) * HD + d;
          float val = acc[mf][nf][r];
          if (which == 2) {
            vd[idx] = f2h(val);
          } else {
            float par = __shfl_xor(val, 1);
            float cc = ct[n * 32 + fi], ss = st[n * 32 + fi];
            float a0 = val * sc, a1 = par * sc;
            float o = (d & 1) ? fmaf(a0, cc, a1 * ss) : fmaf(a0, cc, -(a1 * ss));
            ((which == 0) ? qd : kd)[idx] = (u16)f2bf(o);
          }
        }
      }
    }
  } else {
#pragma unroll
    for (int nf = 0; nf < 4; ++nf) {
      int col = n0 + wn * 64 + nf * 16 + (l & 15);
      float bl_ = bias[col];
#pragma unroll
      for (int mf = 0; mf < 4; ++mf) {
#pragma unroll
        for (int r = 0; r < 4; ++r) {
          int row = m0 + wm * 64 + mf * 16 + (l >> 4) * 4 + r;
          C[(size_t)row * 1024 + col] = acc[mf][nf][r] + bl_;
        }
      }
    }
  }
}

// ---------------- MFMA block attention with on-the-fly coarsening (unchanged) ----------------
#define KP 72   // K LDS pitch (bf16)
#define VP 136  // V^T LDS pitch (fp16)
#define PP 136  // P LDS pitch (fp16)
template <int LV, int FINE>
__global__ __launch_bounds__(256, 2) void attn_mfma_kernel(
    const u16* __restrict__ qg, const u16* __restrict__ kgl, const u16* __restrict__ vg,
    float* __restrict__ yl, float* __restrict__ al) {
  constexpr int R = 1 << LV;
  constexpr float QKSC = 1.0f / (float)R;
  __shared__ __align__(16) u16 Ks[128 * KP];
  __shared__ __align__(16) u16 Vt[64 * VP];
  __shared__ __align__(16) u16 Ps[128 * PP];
  const int t = threadIdx.x;
  const int blk = blockIdx.x, bh = blockIdx.y;
  const int l = t & 63, w = t >> 6;
  const int lr = l & 15, lg = l >> 4;
  const int nl = NTOK >> LV;
  const size_t bbase = (size_t)bh * NTOK;

  s16x8 aq[2][2];
#pragma unroll
  for (int mf = 0; mf < 2; ++mf)
#pragma unroll
    for (int ks = 0; ks < 2; ++ks) {
      int qrow = blk * 128 + w * 32 + mf * 16 + lr;
      const u16* src = qg + (bbase + ((size_t)qrow << LV)) * HD + ks * 32 + lg * 8;
      if (LV == 0) {
        aq[mf][ks] = *(const s16x8*)src;
      } else {
        float s[8] = {};
#pragma unroll
        for (int ss = 0; ss < R; ++ss) {
          uint4 a = *(const uint4*)(src + (size_t)ss * HD);
          float f[8];
          up8(a, f);
#pragma unroll
          for (int c = 0; c < 8; ++c) s[c] += f[c];
        }
        union { uint4 u; s16x8 v; } cv;
        cv.u = make_uint4(pk2(s[0] * QKSC, s[1] * QKSC), pk2(s[2] * QKSC, s[3] * QKSC),
                          pk2(s[4] * QKSC, s[5] * QKSC), pk2(s[6] * QKSC, s[7] * QKSC));
        aq[mf][ks] = cv.v;
      }
    }

  f32x4 zero4 = {0.f, 0.f, 0.f, 0.f};
  f32x4 accY[2][4];
  float asum[2][4];
#pragma unroll
  for (int mf = 0; mf < 2; ++mf)
#pragma unroll
    for (int nf = 0; nf < 4; ++nf) accY[mf][nf] = zero4;
#pragma unroll
  for (int mf = 0; mf < 2; ++mf)
#pragma unroll
    for (int r = 0; r < 4; ++r) asum[mf][r] = 0.f;

  const int npass = FINE ? 2 : 1;
  for (int pass = 0; pass < npass; ++pass) {
    const int kblk = (pass == 0) ? (blk ^ 1) : blk;
    __syncthreads();
#pragma unroll
    for (int it = 0; it < 2; ++it) {
      int kk = it * 64 + (t >> 2), dq = (t & 3) * 16;
      const u16* src = kgl + (bbase + (((size_t)kblk * 128 + kk) << LV)) * HD + dq;
      if (LV == 0) {
        *(uint4*)&Ks[kk * KP + dq] = *(const uint4*)src;
        *(uint4*)&Ks[kk * KP + dq + 8] = *(const uint4*)(src + 8);
      } else {
        float s[16] = {};
#pragma unroll
        for (int ss = 0; ss < R; ++ss) {
          float f[8];
          up8(*(const uint4*)(src + (size_t)ss * HD), f);
#pragma unroll
          for (int c = 0; c < 8; ++c) s[c] += f[c];
          up8(*(const uint4*)(src + (size_t)ss * HD + 8), f);
#pragma unroll
          for (int c = 0; c < 8; ++c) s[8 + c] += f[c];
        }
        u32 pk[8];
#pragma unroll
        for (int j = 0; j < 8; ++j) pk[j] = pk2(s[2 * j] * QKSC, s[2 * j + 1] * QKSC);
        *(uint4*)&Ks[kk * KP + dq] = make_uint4(pk[0], pk[1], pk[2], pk[3]);
        *(uint4*)&Ks[kk * KP + dq + 8] = make_uint4(pk[4], pk[5], pk[6], pk[7]);
      }
    }
#pragma unroll
    for (int it = 0; it < 2; ++it) {
      int kk = it * 64 + (t >> 2), dq = (t & 3) * 16;
      const u16* src = vg + (bbase + (((size_t)kblk * 128 + kk) << LV)) * HD + dq;
      u16 hv[16];
      if (LV == 0) {
        union { uint4 u; u16 h[8]; } a0, a1;
        a0.u = *(const uint4*)src;
        a1.u = *(const uint4*)(src + 8);
#pragma unroll
        for (int c = 0; c < 8; ++c) { hv[c] = a0.h[c]; hv[8 + c] = a1.h[c]; }
      } else {
        float s[16] = {};
#pragma unroll
        for (int ss = 0; ss < R; ++ss) {
          float f[8];
          up8h(*(const uint4*)(src + (size_t)ss * HD), f);
#pragma unroll
          for (int c = 0; c < 8; ++c) s[c] += f[c];
          up8h(*(const uint4*)(src + (size_t)ss * HD + 8), f);
#pragma unroll
          for (int c = 0; c < 8; ++c) s[8 + c] += f[c];
        }
#pragma unroll
        for (int c = 0; c < 16; ++c) hv[c] = f2h(s[c]);
      }
#pragma unroll
      for (int c = 0; c < 16; ++c) {
        int dv = dq + c;
        int col = kk ^ (((dv >> 4) & 1) << 5) ^ (((dv >> 5) & 1) << 3);
        Vt[dv * VP + col] = hv[c];
      }
    }
    __syncthreads();
    f32x4 accS[2][8];
#pragma unroll
    for (int mf = 0; mf < 2; ++mf)
#pragma unroll
      for (int nf = 0; nf < 8; ++nf) accS[mf][nf] = zero4;
#pragma unroll
    for (int nf = 0; nf < 8; ++nf)
#pragma unroll
      for (int ks = 0; ks < 2; ++ks) {
        s16x8 bk = *(const s16x8*)&Ks[(nf * 16 + lr) * KP + ks * 32 + lg * 8];
        accS[0][nf] = MFMA_BF16(aq[0][ks], bk, accS[0][nf]);
        accS[1][nf] = MFMA_BF16(aq[1][ks], bk, accS[1][nf]);
      }
#pragma unroll
    for (int mf = 0; mf < 2; ++mf)
#pragma unroll
      for (int r = 0; r < 4; ++r) {
        float m = accS[mf][0][r];
#pragma unroll
        for (int nf = 1; nf < 8; ++nf) m = fmaxf(m, accS[mf][nf][r]);
#pragma unroll
        for (int xm = 1; xm < 16; xm <<= 1) m = fmaxf(m, __shfl_xor(m, xm));
        float s = 0.f;
#pragma unroll
        for (int nf = 0; nf < 8; ++nf) {
          float e = __expf(accS[mf][nf][r] - m);
          accS[mf][nf][r] = e;
          s += e;
        }
#pragma unroll
        for (int xm = 1; xm < 16; xm <<= 1) s += __shfl_xor(s, xm);
        asum[mf][r] += s;
      }
#pragma unroll
    for (int mf = 0; mf < 2; ++mf)
#pragma unroll
      for (int nf = 0; nf < 8; ++nf)
#pragma unroll
        for (int r = 0; r < 4; ++r) {
          int qrow = w * 32 + mf * 16 + lg * 4 + r;
          int col = (nf * 16 + lr) ^ (((qrow >> 3) & 1) << 4);
          Ps[qrow * PP + col] = f2h(accS[mf][nf][r]);
        }
    __syncthreads();
#pragma unroll
    for (int ks4 = 0; ks4 < 4; ++ks4) {
      f16x8 ap[2];
#pragma unroll
      for (int mf = 0; mf < 2; ++mf) {
        int prow = w * 32 + mf * 16 + lr;
        int koff = (ks4 * 32 + lg * 8) ^ (((lr >> 3) & 1) << 4);
        ap[mf] = *(const f16x8*)&Ps[prow * PP + koff];
      }
#pragma unroll
      for (int nf = 0; nf < 4; ++nf) {
        int koff = (ks4 * 32 + lg * 8) ^ ((nf & 1) << 5) ^ (((nf >> 1) & 1) << 3);
        f16x8 bv = *(const f16x8*)&Vt[(nf * 16 + lr) * VP + koff];
        accY[0][nf] = MFMA_F16(ap[0], bv, accY[0][nf]);
        accY[1][nf] = MFMA_F16(ap[1], bv, accY[1][nf]);
      }
    }
  }
#pragma unroll
  for (int mf = 0; mf < 2; ++mf) {
    if (lr == 0) {
#pragma unroll
      for (int r = 0; r < 4; ++r)
        al[(size_t)bh * nl + blk * 128 + w * 32 + mf * 16 + lg * 4 + r] = asum[mf][r];
    }
#pragma unroll
    for (int nf = 0; nf < 4; ++nf)
#pragma unroll
      for (int r = 0; r < 4; ++r) {
        int qrow = blk * 128 + w * 32 + mf * 16 + lg * 4 + r;
        yl[((size_t)bh * nl + qrow) * HD + nf * 16 + lr] = accY[mf][nf][r];
      }
  }
}

// ---------------- pyramid combine ----------------
__global__ __launch_bounds__(256) void combine_pyr_kernel(
    const float* __restrict__ Yf, const float* __restrict__ Y1, const float* __restrict__ Y2,
    const float* __restrict__ Y3, const float* __restrict__ Y4,
    const float* __restrict__ Af, const float* __restrict__ A1, const float* __restrict__ A2,
    const float* __restrict__ A3, const float* __restrict__ A4, u16* __restrict__ out) {
  int row = blockIdx.x, t = threadIdx.x;  // row = b*4096 + tok
  int b = row >> 12, tok = row & 4095;
  int h = t >> 4, d = (t & 15) * 4;
  int bh = b * NH + h;
  float a = Af[(size_t)bh * 4096 + tok] + A1[(size_t)bh * 2048 + (tok >> 1)] +
            A2[(size_t)bh * 1024 + (tok >> 2)] + A3[(size_t)bh * 512 + (tok >> 3)] +
            A4[(size_t)bh * 256 + (tok >> 4)] + 1e-8f;
  float4 y0 = *(const float4*)&Yf[((size_t)bh * 4096 + tok) * HD + d];
  float4 y1 = *(const float4*)&Y1[((size_t)bh * 2048 + (tok >> 1)) * HD + d];
  float4 y2 = *(const float4*)&Y2[((size_t)bh * 1024 + (tok >> 2)) * HD + d];
  float4 y3 = *(const float4*)&Y3[((size_t)bh * 512 + (tok >> 3)) * HD + d];
  float4 y4 = *(const float4*)&Y4[((size_t)bh * 256 + (tok >> 4)) * HD + d];
  float inv = 1.0f / a;
  float o0 = (y0.x + y1.x + y2.x + y3.x + y4.x) * inv;
  float o1 = (y0.y + y1.y + y2.y + y3.y + y4.y) * inv;
  float o2 = (y0.z + y1.z + y2.z + y3.z + y4.z) * inv;
  float o3 = (y0.w + y1.w + y2.w + y3.w + y4.w) * inv;
  *(uint2*)&out[(size_t)row * HID + t * 4] = make_uint2(pkh2(o0, o1), pkh2(o2, o3));
}

extern "C" void kernel_launch(void* const* d_in, const int* in_sizes, int n_in,
                              void* d_out, int out_size, void* d_ws, size_t ws_size,
                              hipStream_t stream) {
  (void)in_sizes; (void)n_in;
  const float* hs = (const float*)d_in[0];
  const float* gm = (const float*)d_in[1];
  const float* bt = (const float*)d_in[2];
  const float* wqkv = (const float*)d_in[3];
  const float* wout = (const float*)d_in[4];
  const float* bout = (const float*)d_in[5];
  float* out = (float*)d_out;

  const size_t MB = 1024ull * 1024ull;
  unsigned char* base = (unsigned char*)d_ws;
  const size_t need = 232 * MB;
  if (ws_size < need) {  // diagnostic: absmax will read ~ (1000 + ws_MiB)
    fill_kernel<<<(out_size + 255) / 256, 256, 0, stream>>>(out, out_size,
                                                            1000.0f + (float)(ws_size >> 20));
    return;
  }

  u16* Qf = (u16*)(base);                    // 32 MiB bf16 [BH][4096][64]
  u16* Kf = (u16*)(base + 32 * MB);          // 32 MiB bf16
  u16* Vf = (u16*)(base + 64 * MB);          // 32 MiB fp16
  float* YACC = (float*)(base + 96 * MB);    // 64 MiB f32 fine Y
  float* Y1 = (float*)(base + 160 * MB);     // 32 MiB
  float* Y2 = (float*)(base + 192 * MB);     // 16 MiB
  float* Y3 = (float*)(base + 208 * MB);     // 8 MiB
  float* Y4 = (float*)(base + 216 * MB);     // 4 MiB
  float* AACC = (float*)(base + 220 * MB);   // ~2 MiB A pyramid
  float* A1 = AACC + (size_t)BH * 4096;
  float* A2 = A1 + (size_t)BH * 2048;
  float* A3 = A2 + (size_t)BH * 1024;
  float* A4 = A3 + (size_t)BH * 512;
  u16* WQT = (u16*)(base + 223 * MB);        // 6 MiB fp16 [3072][1024]
  u16* WOT = (u16*)(base + 229 * MB);        // 2 MiB fp16 [1024][1024]
  float* CT = (float*)(base + 231 * MB);     // 512 KiB
  float* ST = CT + NTOK * 32;                // 512 KiB
  // overlays (stream-ordered): ALN in YACC region (dead before attn writes YACC);
  // attnout over Qf (dead after attn kernels).
  u16* ALN = (u16*)(base + 96 * MB);         // 32 MiB fp16 [16384][1024]
  u16* ATT = (u16*)(base);                   // 32 MiB fp16 [16384][1024]

  rope_table_kernel<<<(NTOK * 32 + 255) / 256, 256, 0, stream>>>(CT, ST);
  ln_f16_kernel<<<NB * NTOK, 256, 0, stream>>>(hs, gm, bt, ALN);
  prep_w_kernel<<<dim3(48, 16), 256, 0, stream>>>(wqkv, WQT, 3072);
  prep_w_kernel<<<dim3(16, 16), 256, 0, stream>>>(wout, WOT, 1024);

  gemm_f16_kernel<0><<<dim3(24, 128), 256, 0, stream>>>(
      ALN, WQT, Qf, Kf, Vf, CT, ST, nullptr, nullptr);

  attn_mfma_kernel<0, 1><<<dim3(32, BH), 256, 0, stream>>>(Qf, Kf, Vf, YACC, AACC);
  attn_mfma_kernel<1, 0><<<dim3(16, BH), 256, 0, stream>>>(Qf, Kf, Vf, Y1, A1);
  attn_mfma_kernel<2, 0><<<dim3(8, BH), 256, 0, stream>>>(Qf, Kf, Vf, Y2, A2);
  attn_mfma_kernel<3, 0><<<dim3(4, BH), 256, 0, stream>>>(Qf, Kf, Vf, Y3, A3);
  attn_mfma_kernel<4, 0><<<dim3(2, BH), 256, 0, stream>>>(Qf, Kf, Vf, Y4, A4);

  combine_pyr_kernel<<<NB * NTOK, 256, 0, stream>>>(YACC, Y1, Y2, Y3, Y4,
                                                    AACC, A1, A2, A3, A4, ATT);
  gemm_f16_kernel<1><<<dim3(8, 128), 256, 0, stream>>>(
      ATT, WOT, nullptr, nullptr, nullptr, nullptr, nullptr, bout, out);
}

// Round 12
// 580.783 us; speedup vs baseline: 1.0689x; 1.0689x over previous
//
#include <hip/hip_runtime.h>
#include <math.h>

#define NTOK 4096
#define NB 4
#define NH 16
#define HD 64
#define HID 1024
#define BH 64          // NB*NH
#define QSCALE 0.125f  // 64^-0.5

typedef unsigned short u16;
typedef unsigned int u32;
typedef __attribute__((ext_vector_type(8))) _Float16 f16x8;
typedef __attribute__((ext_vector_type(8))) short s16x8;
typedef __attribute__((ext_vector_type(4))) float f32x4;
#define MFMA_F16(a, b, c) __builtin_amdgcn_mfma_f32_16x16x32_f16(a, b, c, 0, 0, 0)
#define MFMA_BF16(a, b, c) __builtin_amdgcn_mfma_f32_16x16x32_bf16(a, b, c, 0, 0, 0)
// async global -> LDS, 16B per lane, dest = wave-uniform base + lane*16
#define GLDS16(gptr, lptr)                                                          \
  __builtin_amdgcn_global_load_lds(                                                \
      (const __attribute__((address_space(1))) void*)(gptr),                       \
      (__attribute__((address_space(3))) void*)(lptr), 16, 0, 0)
#define VMCNT0() asm volatile("s_waitcnt vmcnt(0)" ::: "memory")
#define VMCNT4() asm volatile("s_waitcnt vmcnt(4)" ::: "memory")
#define SCHED_FENCE() __builtin_amdgcn_sched_barrier(0)

__device__ __forceinline__ float bf2f(u32 u) {
  union { u32 i; float f; } x; x.i = u << 16; return x.f;
}
__device__ __forceinline__ u32 f2bf(float f) {
  union { float f; u32 i; } x; x.f = f;
  return (x.i + 0x7fffu + ((x.i >> 16) & 1u)) >> 16;  // RTNE
}
__device__ __forceinline__ u32 pk2(float a, float b) {
  return f2bf(a) | (f2bf(b) << 16);
}
__device__ __forceinline__ u32 pkh2(float a, float b) {  // 2 x f32 -> packed fp16
  _Float16 ha = (_Float16)a, hb = (_Float16)b;
  u16 x, y;
  __builtin_memcpy(&x, &ha, 2);
  __builtin_memcpy(&y, &hb, 2);
  return (u32)x | ((u32)y << 16);
}
__device__ __forceinline__ u16 f2h(float a) {
  _Float16 h = (_Float16)a;
  u16 x;
  __builtin_memcpy(&x, &h, 2);
  return x;
}
__device__ __forceinline__ void up8(uint4 a, float* f) {  // 8 bf16 -> f32
  f[0] = bf2f(a.x & 0xffffu); f[1] = bf2f(a.x >> 16);
  f[2] = bf2f(a.y & 0xffffu); f[3] = bf2f(a.y >> 16);
  f[4] = bf2f(a.z & 0xffffu); f[5] = bf2f(a.z >> 16);
  f[6] = bf2f(a.w & 0xffffu); f[7] = bf2f(a.w >> 16);
}
__device__ __forceinline__ void up8h(uint4 a, float* f) {  // 8 fp16 -> f32
  union { uint4 u; _Float16 h[8]; } x;
  x.u = a;
#pragma unroll
  for (int c = 0; c < 8; ++c) f[c] = (float)x.h[c];
}

// ---------------- diagnostic fill ----------------
__global__ void fill_kernel(float* __restrict__ out, int n, float v) {
  int i = blockIdx.x * 256 + threadIdx.x;
  if (i < n) out[i] = v;
}

// ---------------- RoPE tables ----------------
__global__ void rope_table_kernel(float* __restrict__ ct, float* __restrict__ st) {
  int idx = blockIdx.x * 256 + threadIdx.x;
  if (idx >= NTOK * 32) return;
  int n = idx >> 5, i = idx & 31;
  float t = powf(10000.0f, (float)(2 * i));   // inf for i>=5 -> inv=0 (matches f64 ~1e-245)
  float inv = 1.0f / (t / 64.0f);
  float f = (float)n * inv;
  ct[idx] = cosf(f);
  st[idx] = sinf(f);
}

// ---------------- LayerNorm -> fp16 ----------------
__global__ __launch_bounds__(256) void ln_f16_kernel(const float* __restrict__ in,
                                                     const float* __restrict__ gm,
                                                     const float* __restrict__ bt,
                                                     u16* __restrict__ out) {
  __shared__ float sh[8];
  int row = blockIdx.x, t = threadIdx.x;
  float4 x = ((const float4*)(in + (size_t)row * HID))[t];
  float s1 = x.x + x.y + x.z + x.w;
  float s2 = x.x * x.x + x.y * x.y + x.z * x.z + x.w * x.w;
#pragma unroll
  for (int o = 32; o > 0; o >>= 1) {
    s1 += __shfl_down(s1, o, 64);
    s2 += __shfl_down(s2, o, 64);
  }
  if ((t & 63) == 0) { sh[t >> 6] = s1; sh[4 + (t >> 6)] = s2; }
  __syncthreads();
  float S1 = sh[0] + sh[1] + sh[2] + sh[3];
  float S2 = sh[4] + sh[5] + sh[6] + sh[7];
  float mu = S1 * (1.0f / HID);
  float var = S2 * (1.0f / HID) - mu * mu;
  float rstd = 1.0f / sqrtf(var + 1e-5f);
  float4 g = ((const float4*)gm)[t], b = ((const float4*)bt)[t];
  float o0 = (x.x - mu) * rstd * g.x + b.x;
  float o1 = (x.y - mu) * rstd * g.y + b.y;
  float o2 = (x.z - mu) * rstd * g.z + b.z;
  float o3 = (x.w - mu) * rstd * g.w + b.w;
  *(uint2*)&out[(size_t)row * HID + t * 4] = make_uint2(pkh2(o0, o1), pkh2(o2, o3));
}

// ---------------- weight prep: w [1024][N] f32 -> w^T fp16 [N][1024] ----------------
__global__ __launch_bounds__(256) void prep_w_kernel(const float* __restrict__ w,
                                                     u16* __restrict__ wt, int N) {
  __shared__ float T[64][65];
  int t = threadIdx.x;
  int n0 = blockIdx.x * 64, k0 = blockIdx.y * 64;
  {
    int k = t >> 2, nc = (t & 3) * 16;
    const float* src = w + (size_t)(k0 + k) * N + n0 + nc;
#pragma unroll
    for (int i = 0; i < 4; ++i) {
      float4 x = *(const float4*)(src + i * 4);
      T[nc + i * 4 + 0][k] = x.x;
      T[nc + i * 4 + 1][k] = x.y;
      T[nc + i * 4 + 2][k] = x.z;
      T[nc + i * 4 + 3][k] = x.w;
    }
  }
  __syncthreads();
  {
    int n = t >> 2, kc = (t & 3) * 16;
    u32 pk[8];
#pragma unroll
    for (int j = 0; j < 8; ++j) pk[j] = pkh2(T[n][kc + 2 * j], T[n][kc + 2 * j + 1]);
    size_t dst = (size_t)(n0 + n) * 1024 + k0 + kc;
    *(uint4*)&wt[dst] = make_uint4(pk[0], pk[1], pk[2], pk[3]);
    *(uint4*)&wt[dst + 8] = make_uint4(pk[4], pk[5], pk[6], pk[7]);
  }
}

// ---------------- fp16 MFMA GEMM, 128x128 tile, BK=32, 4 waves ----------------
// T4 counted-vmcnt pipeline: TRIPLE-buffered LDS, prefetch distance 2,
// steady-state s_waitcnt vmcnt(4) (never 0) + raw s_barrier per K-step.
template <int MODE>
__global__ __launch_bounds__(256) void gemm_f16_kernel(
    const u16* __restrict__ At, const u16* __restrict__ Bt,
    u16* __restrict__ qd, u16* __restrict__ kd, u16* __restrict__ vd,
    const float* __restrict__ ct, const float* __restrict__ st,
    const float* __restrict__ bias, float* __restrict__ C) {
  constexpr int BUF = 128 * 32;  // u16 per buffer
  __shared__ __align__(16) u16 As[3 * BUF], Bs[3 * BUF];
  const int t = threadIdx.x;
  const int m0 = blockIdx.y * 128, n0 = blockIdx.x * 128;
  const int l = t & 63, w = t >> 6;
  const int wm = w & 1, wn = w >> 1;
  const int lr = l & 15, kg = (l >> 4) * 8;

  // staging: wave w covers rows [32w, 32w+32); lane l -> row +(l>>2), 16B chunk (l&3)
  const u16* gA = At + (size_t)(m0 + w * 32 + (l >> 2)) * 1024 + (l & 3) * 8;
  const u16* gB = Bt + (size_t)(n0 + w * 32 + (l >> 2)) * 1024 + (l & 3) * 8;
  const int wbase = (w * 32) * 32;  // wave-uniform LDS base offset (u16 units)

  f32x4 zero4 = {0.f, 0.f, 0.f, 0.f};
  f32x4 acc[4][4];
#pragma unroll
  for (int mf = 0; mf < 4; ++mf)
#pragma unroll
    for (int nf = 0; nf < 4; ++nf) acc[mf][nf] = zero4;

  // prologue: stage tiles 0 and 1 into buffers 0 and 1
  GLDS16(gA, &As[wbase]);
  GLDS16(gA + (size_t)16 * 1024, &As[wbase + 16 * 32]);
  GLDS16(gB, &Bs[wbase]);
  GLDS16(gB + (size_t)16 * 1024, &Bs[wbase + 16 * 32]);
  GLDS16(gA + 32, &As[BUF + wbase]);
  GLDS16(gA + 32 + (size_t)16 * 1024, &As[BUF + wbase + 16 * 32]);
  GLDS16(gB + 32, &Bs[BUF + wbase]);
  GLDS16(gB + 32 + (size_t)16 * 1024, &Bs[BUF + wbase + 16 * 32]);
  VMCNT4();  // tile 0 landed (tile 1's 4 loads still in flight)
  __builtin_amdgcn_s_barrier();
  SCHED_FENCE();

  int cur = 0;
  for (int step = 0; step < 32; ++step) {
    int nx2 = cur + 2; if (nx2 >= 3) nx2 -= 3;
    if (step + 2 < 32) {  // issue tile step+2 -> buf[(cur+2)%3]
      int k2 = (step + 2) * 32;
      GLDS16(gA + k2, &As[nx2 * BUF + wbase]);
      GLDS16(gA + k2 + (size_t)16 * 1024, &As[nx2 * BUF + wbase + 16 * 32]);
      GLDS16(gB + k2, &Bs[nx2 * BUF + wbase]);
      GLDS16(gB + k2 + (size_t)16 * 1024, &Bs[nx2 * BUF + wbase + 16 * 32]);
    }
    {  // compute on buf[cur]
      const int cb = cur * BUF;
      f16x8 af[4];
#pragma unroll
      for (int mf = 0; mf < 4; ++mf)
        af[mf] = *(const f16x8*)&As[cb + (wm * 64 + mf * 16 + lr) * 32 + kg];
#pragma unroll
      for (int nf = 0; nf < 4; ++nf) {
        f16x8 bf = *(const f16x8*)&Bs[cb + (wn * 64 + nf * 16 + lr) * 32 + kg];
#pragma unroll
        for (int mf = 0; mf < 4; ++mf) acc[mf][nf] = MFMA_F16(af[mf], bf, acc[mf][nf]);
      }
    }
    if (step + 1 < 32) {
      SCHED_FENCE();  // pin this step's ds_read+MFMA above the wait/barrier
      if (step + 2 < 32) VMCNT4();  // tile step+1 landed; step+2's 4 loads in flight
      else               VMCNT0();  // nothing left in flight to hide behind
      __builtin_amdgcn_s_barrier();
      SCHED_FENCE();  // pin next step below the barrier
    }
    cur = cur + 1; if (cur >= 3) cur -= 3;
  }

  if (MODE == 0) {
#pragma unroll
    for (int nf = 0; nf < 4; ++nf) {
      int col = n0 + wn * 64 + nf * 16 + (l & 15);
      int which = col >> 10;            // wave-uniform: 0:q 1:k 2:v
      int rem = col & 1023;
      int h = rem >> 6, d = rem & 63;
      int fi = d >> 1;
      float sc = (which == 0) ? QSCALE : 1.0f;
#pragma unroll
      for (int mf = 0; mf < 4; ++mf) {
#pragma unroll
        for (int r = 0; r < 4; ++r) {
          int row = m0 + wm * 64 + mf * 16 + (l >> 4) * 4 + r;
          int bbo = row >> 12, n = row & 4095;
          size_t idx = ((size_t)(bbo * NH + h) * NTOK + n) * HD + d;
          float val = acc[mf][nf][r];
          if (which == 2) {
            vd[idx] = f2h(val);
          } else {
            float par = __shfl_xor(val, 1);
            float cc = ct[n * 32 + fi], ss = st[n * 32 + fi];
            float a0 = val * sc, a1 = par * sc;
            float o = (d & 1) ? fmaf(a0, cc, a1 * ss) : fmaf(a0, cc, -(a1 * ss));
            ((which == 0) ? qd : kd)[idx] = (u16)f2bf(o);
          }
        }
      }
    }
  } else {
#pragma unroll
    for (int nf = 0; nf < 4; ++nf) {
      int col = n0 + wn * 64 + nf * 16 + (l & 15);
      float bl_ = bias[col];
#pragma unroll
      for (int mf = 0; mf < 4; ++mf) {
#pragma unroll
        for (int r = 0; r < 4; ++r) {
          int row = m0 + wm * 64 + mf * 16 + (l >> 4) * 4 + r;
          C[(size_t)row * 1024 + col] = acc[mf][nf][r] + bl_;
        }
      }
    }
  }
}

// ---------------- MFMA block attention with on-the-fly coarsening (unchanged) ----------------
#define KP 72   // K LDS pitch (bf16)
#define VP 136  // V^T LDS pitch (fp16)
#define PP 136  // P LDS pitch (fp16)
template <int LV, int FINE>
__global__ __launch_bounds__(256, 2) void attn_mfma_kernel(
    const u16* __restrict__ qg, const u16* __restrict__ kgl, const u16* __restrict__ vg,
    float* __restrict__ yl, float* __restrict__ al) {
  constexpr int R = 1 << LV;
  constexpr float QKSC = 1.0f / (float)R;
  __shared__ __align__(16) u16 Ks[128 * KP];
  __shared__ __align__(16) u16 Vt[64 * VP];
  __shared__ __align__(16) u16 Ps[128 * PP];
  const int t = threadIdx.x;
  const int blk = blockIdx.x, bh = blockIdx.y;
  const int l = t & 63, w = t >> 6;
  const int lr = l & 15, lg = l >> 4;
  const int nl = NTOK >> LV;
  const size_t bbase = (size_t)bh * NTOK;

  s16x8 aq[2][2];
#pragma unroll
  for (int mf = 0; mf < 2; ++mf)
#pragma unroll
    for (int ks = 0; ks < 2; ++ks) {
      int qrow = blk * 128 + w * 32 + mf * 16 + lr;
      const u16* src = qg + (bbase + ((size_t)qrow << LV)) * HD + ks * 32 + lg * 8;
      if (LV == 0) {
        aq[mf][ks] = *(const s16x8*)src;
      } else {
        float s[8] = {};
#pragma unroll
        for (int ss = 0; ss < R; ++ss) {
          uint4 a = *(const uint4*)(src + (size_t)ss * HD);
          float f[8];
          up8(a, f);
#pragma unroll
          for (int c = 0; c < 8; ++c) s[c] += f[c];
        }
        union { uint4 u; s16x8 v; } cv;
        cv.u = make_uint4(pk2(s[0] * QKSC, s[1] * QKSC), pk2(s[2] * QKSC, s[3] * QKSC),
                          pk2(s[4] * QKSC, s[5] * QKSC), pk2(s[6] * QKSC, s[7] * QKSC));
        aq[mf][ks] = cv.v;
      }
    }

  f32x4 zero4 = {0.f, 0.f, 0.f, 0.f};
  f32x4 accY[2][4];
  float asum[2][4];
#pragma unroll
  for (int mf = 0; mf < 2; ++mf)
#pragma unroll
    for (int nf = 0; nf < 4; ++nf) accY[mf][nf] = zero4;
#pragma unroll
  for (int mf = 0; mf < 2; ++mf)
#pragma unroll
    for (int r = 0; r < 4; ++r) asum[mf][r] = 0.f;

  const int npass = FINE ? 2 : 1;
  for (int pass = 0; pass < npass; ++pass) {
    const int kblk = (pass == 0) ? (blk ^ 1) : blk;
    __syncthreads();
#pragma unroll
    for (int it = 0; it < 2; ++it) {
      int kk = it * 64 + (t >> 2), dq = (t & 3) * 16;
      const u16* src = kgl + (bbase + (((size_t)kblk * 128 + kk) << LV)) * HD + dq;
      if (LV == 0) {
        *(uint4*)&Ks[kk * KP + dq] = *(const uint4*)src;
        *(uint4*)&Ks[kk * KP + dq + 8] = *(const uint4*)(src + 8);
      } else {
        float s[16] = {};
#pragma unroll
        for (int ss = 0; ss < R; ++ss) {
          float f[8];
          up8(*(const uint4*)(src + (size_t)ss * HD), f);
#pragma unroll
          for (int c = 0; c < 8; ++c) s[c] += f[c];
          up8(*(const uint4*)(src + (size_t)ss * HD + 8), f);
#pragma unroll
          for (int c = 0; c < 8; ++c) s[8 + c] += f[c];
        }
        u32 pk[8];
#pragma unroll
        for (int j = 0; j < 8; ++j) pk[j] = pk2(s[2 * j] * QKSC, s[2 * j + 1] * QKSC);
        *(uint4*)&Ks[kk * KP + dq] = make_uint4(pk[0], pk[1], pk[2], pk[3]);
        *(uint4*)&Ks[kk * KP + dq + 8] = make_uint4(pk[4], pk[5], pk[6], pk[7]);
      }
    }
#pragma unroll
    for (int it = 0; it < 2; ++it) {
      int kk = it * 64 + (t >> 2), dq = (t & 3) * 16;
      const u16* src = vg + (bbase + (((size_t)kblk * 128 + kk) << LV)) * HD + dq;
      u16 hv[16];
      if (LV == 0) {
        union { uint4 u; u16 h[8]; } a0, a1;
        a0.u = *(const uint4*)src;
        a1.u = *(const uint4*)(src + 8);
#pragma unroll
        for (int c = 0; c < 8; ++c) { hv[c] = a0.h[c]; hv[8 + c] = a1.h[c]; }
      } else {
        float s[16] = {};
#pragma unroll
        for (int ss = 0; ss < R; ++ss) {
          float f[8];
          up8h(*(const uint4*)(src + (size_t)ss * HD), f);
#pragma unroll
          for (int c = 0; c < 8; ++c) s[c] += f[c];
          up8h(*(const uint4*)(src + (size_t)ss * HD + 8), f);
#pragma unroll
          for (int c = 0; c < 8; ++c) s[8 + c] += f[c];
        }
#pragma unroll
        for (int c = 0; c < 16; ++c) hv[c] = f2h(s[c]);
      }
#pragma unroll
      for (int c = 0; c < 16; ++c) {
        int dv = dq + c;
        int col = kk ^ (((dv >> 4) & 1) << 5) ^ (((dv >> 5) & 1) << 3);
        Vt[dv * VP + col] = hv[c];
      }
    }
    __syncthreads();
    f32x4 accS[2][8];
#pragma unroll
    for (int mf = 0; mf < 2; ++mf)
#pragma unroll
      for (int nf = 0; nf < 8; ++nf) accS[mf][nf] = zero4;
#pragma unroll
    for (int nf = 0; nf < 8; ++nf)
#pragma unroll
      for (int ks = 0; ks < 2; ++ks) {
        s16x8 bk = *(const s16x8*)&Ks[(nf * 16 + lr) * KP + ks * 32 + lg * 8];
        accS[0][nf] = MFMA_BF16(aq[0][ks], bk, accS[0][nf]);
        accS[1][nf] = MFMA_BF16(aq[1][ks], bk, accS[1][nf]);
      }
#pragma unroll
    for (int mf = 0; mf < 2; ++mf)
#pragma unroll
      for (int r = 0; r < 4; ++r) {
        float m = accS[mf][0][r];
#pragma unroll
        for (int nf = 1; nf < 8; ++nf) m = fmaxf(m, accS[mf][nf][r]);
#pragma unroll
        for (int xm = 1; xm < 16; xm <<= 1) m = fmaxf(m, __shfl_xor(m, xm));
        float s = 0.f;
#pragma unroll
        for (int nf = 0; nf < 8; ++nf) {
          float e = __expf(accS[mf][nf][r] - m);
          accS[mf][nf][r] = e;
          s += e;
        }
#pragma unroll
        for (int xm = 1; xm < 16; xm <<= 1) s += __shfl_xor(s, xm);
        asum[mf][r] += s;
      }
#pragma unroll
    for (int mf = 0; mf < 2; ++mf)
#pragma unroll
      for (int nf = 0; nf < 8; ++nf)
#pragma unroll
        for (int r = 0; r < 4; ++r) {
          int qrow = w * 32 + mf * 16 + lg * 4 + r;
          int col = (nf * 16 + lr) ^ (((qrow >> 3) & 1) << 4);
          Ps[qrow * PP + col] = f2h(accS[mf][nf][r]);
        }
    __syncthreads();
#pragma unroll
    for (int ks4 = 0; ks4 < 4; ++ks4) {
      f16x8 ap[2];
#pragma unroll
      for (int mf = 0; mf < 2; ++mf) {
        int prow = w * 32 + mf * 16 + lr;
        int koff = (ks4 * 32 + lg * 8) ^ (((lr >> 3) & 1) << 4);
        ap[mf] = *(const f16x8*)&Ps[prow * PP + koff];
      }
#pragma unroll
      for (int nf = 0; nf < 4; ++nf) {
        int koff = (ks4 * 32 + lg * 8) ^ ((nf & 1) << 5) ^ (((nf >> 1) & 1) << 3);
        f16x8 bv = *(const f16x8*)&Vt[(nf * 16 + lr) * VP + koff];
        accY[0][nf] = MFMA_F16(ap[0], bv, accY[0][nf]);
        accY[1][nf] = MFMA_F16(ap[1], bv, accY[1][nf]);
      }
    }
  }
#pragma unroll
  for (int mf = 0; mf < 2; ++mf) {
    if (lr == 0) {
#pragma unroll
      for (int r = 0; r < 4; ++r)
        al[(size_t)bh * nl + blk * 128 + w * 32 + mf * 16 + lg * 4 + r] = asum[mf][r];
    }
#pragma unroll
    for (int nf = 0; nf < 4; ++nf)
#pragma unroll
      for (int r = 0; r < 4; ++r) {
        int qrow = blk * 128 + w * 32 + mf * 16 + lg * 4 + r;
        yl[((size_t)bh * nl + qrow) * HD + nf * 16 + lr] = accY[mf][nf][r];
      }
  }
}

// ---------------- pyramid combine ----------------
__global__ __launch_bounds__(256) void combine_pyr_kernel(
    const float* __restrict__ Yf, const float* __restrict__ Y1, const float* __restrict__ Y2,
    const float* __restrict__ Y3, const float* __restrict__ Y4,
    const float* __restrict__ Af, const float* __restrict__ A1, const float* __restrict__ A2,
    const float* __restrict__ A3, const float* __restrict__ A4, u16* __restrict__ out) {
  int row = blockIdx.x, t = threadIdx.x;  // row = b*4096 + tok
  int b = row >> 12, tok = row & 4095;
  int h = t >> 4, d = (t & 15) * 4;
  int bh = b * NH + h;
  float a = Af[(size_t)bh * 4096 + tok] + A1[(size_t)bh * 2048 + (tok >> 1)] +
            A2[(size_t)bh * 1024 + (tok >> 2)] + A3[(size_t)bh * 512 + (tok >> 3)] +
            A4[(size_t)bh * 256 + (tok >> 4)] + 1e-8f;
  float4 y0 = *(const float4*)&Yf[((size_t)bh * 4096 + tok) * HD + d];
  float4 y1 = *(const float4*)&Y1[((size_t)bh * 2048 + (tok >> 1)) * HD + d];
  float4 y2 = *(const float4*)&Y2[((size_t)bh * 1024 + (tok >> 2)) * HD + d];
  float4 y3 = *(const float4*)&Y3[((size_t)bh * 512 + (tok >> 3)) * HD + d];
  float4 y4 = *(const float4*)&Y4[((size_t)bh * 256 + (tok >> 4)) * HD + d];
  float inv = 1.0f / a;
  float o0 = (y0.x + y1.x + y2.x + y3.x + y4.x) * inv;
  float o1 = (y0.y + y1.y + y2.y + y3.y + y4.y) * inv;
  float o2 = (y0.z + y1.z + y2.z + y3.z + y4.z) * inv;
  float o3 = (y0.w + y1.w + y2.w + y3.w + y4.w) * inv;
  *(uint2*)&out[(size_t)row * HID + t * 4] = make_uint2(pkh2(o0, o1), pkh2(o2, o3));
}

extern "C" void kernel_launch(void* const* d_in, const int* in_sizes, int n_in,
                              void* d_out, int out_size, void* d_ws, size_t ws_size,
                              hipStream_t stream) {
  (void)in_sizes; (void)n_in;
  const float* hs = (const float*)d_in[0];
  const float* gm = (const float*)d_in[1];
  const float* bt = (const float*)d_in[2];
  const float* wqkv = (const float*)d_in[3];
  const float* wout = (const float*)d_in[4];
  const float* bout = (const float*)d_in[5];
  float* out = (float*)d_out;

  const size_t MB = 1024ull * 1024ull;
  unsigned char* base = (unsigned char*)d_ws;
  const size_t need = 232 * MB;
  if (ws_size < need) {  // diagnostic: absmax will read ~ (1000 + ws_MiB)
    fill_kernel<<<(out_size + 255) / 256, 256, 0, stream>>>(out, out_size,
                                                            1000.0f + (float)(ws_size >> 20));
    return;
  }

  u16* Qf = (u16*)(base);                    // 32 MiB bf16 [BH][4096][64]
  u16* Kf = (u16*)(base + 32 * MB);          // 32 MiB bf16
  u16* Vf = (u16*)(base + 64 * MB);          // 32 MiB fp16
  float* YACC = (float*)(base + 96 * MB);    // 64 MiB f32 fine Y
  float* Y1 = (float*)(base + 160 * MB);     // 32 MiB
  float* Y2 = (float*)(base + 192 * MB);     // 16 MiB
  float* Y3 = (float*)(base + 208 * MB);     // 8 MiB
  float* Y4 = (float*)(base + 216 * MB);     // 4 MiB
  float* AACC = (float*)(base + 220 * MB);   // ~2 MiB A pyramid
  float* A1 = AACC + (size_t)BH * 4096;
  float* A2 = A1 + (size_t)BH * 2048;
  float* A3 = A2 + (size_t)BH * 1024;
  float* A4 = A3 + (size_t)BH * 512;
  u16* WQT = (u16*)(base + 223 * MB);        // 6 MiB fp16 [3072][1024]
  u16* WOT = (u16*)(base + 229 * MB);        // 2 MiB fp16 [1024][1024]
  float* CT = (float*)(base + 231 * MB);     // 512 KiB
  float* ST = CT + NTOK * 32;                // 512 KiB
  // overlays (stream-ordered): ALN in YACC region (dead before attn writes YACC);
  // attnout over Qf (dead after attn kernels).
  u16* ALN = (u16*)(base + 96 * MB);         // 32 MiB fp16 [16384][1024]
  u16* ATT = (u16*)(base);                   // 32 MiB fp16 [16384][1024]

  rope_table_kernel<<<(NTOK * 32 + 255) / 256, 256, 0, stream>>>(CT, ST);
  ln_f16_kernel<<<NB * NTOK, 256, 0, stream>>>(hs, gm, bt, ALN);
  prep_w_kernel<<<dim3(48, 16), 256, 0, stream>>>(wqkv, WQT, 3072);
  prep_w_kernel<<<dim3(16, 16), 256, 0, stream>>>(wout, WOT, 1024);

  gemm_f16_kernel<0><<<dim3(24, 128), 256, 0, stream>>>(
      ALN, WQT, Qf, Kf, Vf, CT, ST, nullptr, nullptr);

  attn_mfma_kernel<0, 1><<<dim3(32, BH), 256, 0, stream>>>(Qf, Kf, Vf, YACC, AACC);
  attn_mfma_kernel<1, 0><<<dim3(16, BH), 256, 0, stream>>>(Qf, Kf, Vf, Y1, A1);
  attn_mfma_kernel<2, 0><<<dim3(8, BH), 256, 0, stream>>>(Qf, Kf, Vf, Y2, A2);
  attn_mfma_kernel<3, 0><<<dim3(4, BH), 256, 0, stream>>>(Qf, Kf, Vf, Y3, A3);
  attn_mfma_kernel<4, 0><<<dim3(2, BH), 256, 0, stream>>>(Qf, Kf, Vf, Y4, A4);

  combine_pyr_kernel<<<NB * NTOK, 256, 0, stream>>>(YACC, Y1, Y2, Y3, Y4,
                                                    AACC, A1, A2, A3, A4, ATT);
  gemm_f16_kernel<1><<<dim3(8, 128), 256, 0, stream>>>(
      ATT, WOT, nullptr, nullptr, nullptr, nullptr, nullptr, bout, out);
}

// Round 13
// 561.823 us; speedup vs baseline: 1.1050x; 1.0337x over previous
//
#include <hip/hip_runtime.h>
#include <math.h>

#define NTOK 4096
#define NB 4
#define NH 16
#define HD 64
#define HID 1024
#define BH 64          // NB*NH
#define QSCALE 0.125f  // 64^-0.5

typedef unsigned short u16;
typedef unsigned int u32;
typedef __attribute__((ext_vector_type(8))) _Float16 f16x8;
typedef __attribute__((ext_vector_type(8))) short s16x8;
typedef __attribute__((ext_vector_type(4))) float f32x4;
#define MFMA_F16(a, b, c) __builtin_amdgcn_mfma_f32_16x16x32_f16(a, b, c, 0, 0, 0)
#define MFMA_BF16(a, b, c) __builtin_amdgcn_mfma_f32_16x16x32_bf16(a, b, c, 0, 0, 0)
// async global -> LDS, 16B per lane, dest = wave-uniform base + lane*16
#define GLDS16(gptr, lptr)                                                          \
  __builtin_amdgcn_global_load_lds(                                                \
      (const __attribute__((address_space(1))) void*)(gptr),                       \
      (__attribute__((address_space(3))) void*)(lptr), 16, 0, 0)
#define VMCNT0() asm volatile("s_waitcnt vmcnt(0)" ::: "memory")
#define VMCNT4() asm volatile("s_waitcnt vmcnt(4)" ::: "memory")
#define SCHED_FENCE() __builtin_amdgcn_sched_barrier(0)

__device__ __forceinline__ float bf2f(u32 u) {
  union { u32 i; float f; } x; x.i = u << 16; return x.f;
}
__device__ __forceinline__ u32 f2bf(float f) {
  union { float f; u32 i; } x; x.f = f;
  return (x.i + 0x7fffu + ((x.i >> 16) & 1u)) >> 16;  // RTNE
}
__device__ __forceinline__ u32 pk2(float a, float b) {
  return f2bf(a) | (f2bf(b) << 16);
}
__device__ __forceinline__ u32 pkh2(float a, float b) {  // 2 x f32 -> packed fp16
  _Float16 ha = (_Float16)a, hb = (_Float16)b;
  u16 x, y;
  __builtin_memcpy(&x, &ha, 2);
  __builtin_memcpy(&y, &hb, 2);
  return (u32)x | ((u32)y << 16);
}
__device__ __forceinline__ u16 f2h(float a) {
  _Float16 h = (_Float16)a;
  u16 x;
  __builtin_memcpy(&x, &h, 2);
  return x;
}
__device__ __forceinline__ void up8(uint4 a, float* f) {  // 8 bf16 -> f32
  f[0] = bf2f(a.x & 0xffffu); f[1] = bf2f(a.x >> 16);
  f[2] = bf2f(a.y & 0xffffu); f[3] = bf2f(a.y >> 16);
  f[4] = bf2f(a.z & 0xffffu); f[5] = bf2f(a.z >> 16);
  f[6] = bf2f(a.w & 0xffffu); f[7] = bf2f(a.w >> 16);
}
__device__ __forceinline__ void up8h(uint4 a, float* f) {  // 8 fp16 -> f32
  union { uint4 u; _Float16 h[8]; } x;
  x.u = a;
#pragma unroll
  for (int c = 0; c < 8; ++c) f[c] = (float)x.h[c];
}

// ---------------- diagnostic fill ----------------
__global__ void fill_kernel(float* __restrict__ out, int n, float v) {
  int i = blockIdx.x * 256 + threadIdx.x;
  if (i < n) out[i] = v;
}

// ---------------- RoPE tables ----------------
__global__ void rope_table_kernel(float* __restrict__ ct, float* __restrict__ st) {
  int idx = blockIdx.x * 256 + threadIdx.x;
  if (idx >= NTOK * 32) return;
  int n = idx >> 5, i = idx & 31;
  float t = powf(10000.0f, (float)(2 * i));   // inf for i>=5 -> inv=0 (matches f64 ~1e-245)
  float inv = 1.0f / (t / 64.0f);
  float f = (float)n * inv;
  ct[idx] = cosf(f);
  st[idx] = sinf(f);
}

// ---------------- LayerNorm -> fp16 ----------------
__global__ __launch_bounds__(256) void ln_f16_kernel(const float* __restrict__ in,
                                                     const float* __restrict__ gm,
                                                     const float* __restrict__ bt,
                                                     u16* __restrict__ out) {
  __shared__ float sh[8];
  int row = blockIdx.x, t = threadIdx.x;
  float4 x = ((const float4*)(in + (size_t)row * HID))[t];
  float s1 = x.x + x.y + x.z + x.w;
  float s2 = x.x * x.x + x.y * x.y + x.z * x.z + x.w * x.w;
#pragma unroll
  for (int o = 32; o > 0; o >>= 1) {
    s1 += __shfl_down(s1, o, 64);
    s2 += __shfl_down(s2, o, 64);
  }
  if ((t & 63) == 0) { sh[t >> 6] = s1; sh[4 + (t >> 6)] = s2; }
  __syncthreads();
  float S1 = sh[0] + sh[1] + sh[2] + sh[3];
  float S2 = sh[4] + sh[5] + sh[6] + sh[7];
  float mu = S1 * (1.0f / HID);
  float var = S2 * (1.0f / HID) - mu * mu;
  float rstd = 1.0f / sqrtf(var + 1e-5f);
  float4 g = ((const float4*)gm)[t], b = ((const float4*)bt)[t];
  float o0 = (x.x - mu) * rstd * g.x + b.x;
  float o1 = (x.y - mu) * rstd * g.y + b.y;
  float o2 = (x.z - mu) * rstd * g.z + b.z;
  float o3 = (x.w - mu) * rstd * g.w + b.w;
  *(uint2*)&out[(size_t)row * HID + t * 4] = make_uint2(pkh2(o0, o1), pkh2(o2, o3));
}

// ---------------- weight prep: w [1024][N] f32 -> w^T fp16 [N][1024] ----------------
__global__ __launch_bounds__(256) void prep_w_kernel(const float* __restrict__ w,
                                                     u16* __restrict__ wt, int N) {
  __shared__ float T[64][65];
  int t = threadIdx.x;
  int n0 = blockIdx.x * 64, k0 = blockIdx.y * 64;
  {
    int k = t >> 2, nc = (t & 3) * 16;
    const float* src = w + (size_t)(k0 + k) * N + n0 + nc;
#pragma unroll
    for (int i = 0; i < 4; ++i) {
      float4 x = *(const float4*)(src + i * 4);
      T[nc + i * 4 + 0][k] = x.x;
      T[nc + i * 4 + 1][k] = x.y;
      T[nc + i * 4 + 2][k] = x.z;
      T[nc + i * 4 + 3][k] = x.w;
    }
  }
  __syncthreads();
  {
    int n = t >> 2, kc = (t & 3) * 16;
    u32 pk[8];
#pragma unroll
    for (int j = 0; j < 8; ++j) pk[j] = pkh2(T[n][kc + 2 * j], T[n][kc + 2 * j + 1]);
    size_t dst = (size_t)(n0 + n) * 1024 + k0 + kc;
    *(uint4*)&wt[dst] = make_uint4(pk[0], pk[1], pk[2], pk[3]);
    *(uint4*)&wt[dst + 8] = make_uint4(pk[4], pk[5], pk[6], pk[7]);
  }
}

// ---------------- fp16 MFMA GEMM, 128x128 tile, BK=32, 4 waves ----------------
// T4 counted-vmcnt pipeline (triple-buffer, depth 2, vmcnt(4)) +
// T2 LDS chunk swizzle via pre-swizzled global source (bank-conflict-free reads) +
// T1 bijective XCD-chunked grid swizzle (A-panel reuse within one XCD's L2).
template <int MODE>
__global__ __launch_bounds__(256) void gemm_f16_kernel(
    const u16* __restrict__ At, const u16* __restrict__ Bt,
    u16* __restrict__ qd, u16* __restrict__ kd, u16* __restrict__ vd,
    const float* __restrict__ ct, const float* __restrict__ st,
    const float* __restrict__ bias, float* __restrict__ C, int nxb) {
  constexpr int BUF = 128 * 32;  // u16 per buffer
  __shared__ __align__(16) u16 As[3 * BUF], Bs[3 * BUF];
  const int t = threadIdx.x;
  // T1: XCD-chunked bijective remap (gridDim.x % 8 == 0)
  const int nwg = gridDim.x;
  const int bid = blockIdx.x;
  const int wid = (bid & 7) * (nwg >> 3) + (bid >> 3);
  const int m0 = (wid / nxb) * 128, n0 = (wid % nxb) * 128;
  const int l = t & 63, w = t >> 6;
  const int wm = w & 1, wn = w >> 1;
  const int lr = l & 15;
  // T2 read-side: physical chunk = lg ^ ((row>>1)&3); row ≡ lr (mod 16-multiples of 8)
  const int kgs = (((l >> 4) ^ ((lr >> 1) & 3))) * 8;

  // staging: wave w covers rows [32w,32w+32); lane l -> row +(l>>2), SOURCE chunk pre-swizzled
  const int schunk = (l & 3) ^ ((l >> 3) & 3);  // = (l&3) ^ f(row), f = ((l>>2)>>1)&3
  const u16* gA = At + (size_t)(m0 + w * 32 + (l >> 2)) * 1024 + schunk * 8;
  const u16* gB = Bt + (size_t)(n0 + w * 32 + (l >> 2)) * 1024 + schunk * 8;
  const int wbase = (w * 32) * 32;  // wave-uniform LDS base offset (u16 units)

  f32x4 zero4 = {0.f, 0.f, 0.f, 0.f};
  f32x4 acc[4][4];
#pragma unroll
  for (int mf = 0; mf < 4; ++mf)
#pragma unroll
    for (int nf = 0; nf < 4; ++nf) acc[mf][nf] = zero4;

  // prologue: stage tiles 0 and 1 into buffers 0 and 1
  GLDS16(gA, &As[wbase]);
  GLDS16(gA + (size_t)16 * 1024, &As[wbase + 16 * 32]);
  GLDS16(gB, &Bs[wbase]);
  GLDS16(gB + (size_t)16 * 1024, &Bs[wbase + 16 * 32]);
  GLDS16(gA + 32, &As[BUF + wbase]);
  GLDS16(gA + 32 + (size_t)16 * 1024, &As[BUF + wbase + 16 * 32]);
  GLDS16(gB + 32, &Bs[BUF + wbase]);
  GLDS16(gB + 32 + (size_t)16 * 1024, &Bs[BUF + wbase + 16 * 32]);
  VMCNT4();  // tile 0 landed (tile 1's 4 loads still in flight)
  __builtin_amdgcn_s_barrier();
  SCHED_FENCE();

  int cur = 0;
  for (int step = 0; step < 32; ++step) {
    int nx2 = cur + 2; if (nx2 >= 3) nx2 -= 3;
    if (step + 2 < 32) {  // issue tile step+2 -> buf[(cur+2)%3]
      int k2 = (step + 2) * 32;
      GLDS16(gA + k2, &As[nx2 * BUF + wbase]);
      GLDS16(gA + k2 + (size_t)16 * 1024, &As[nx2 * BUF + wbase + 16 * 32]);
      GLDS16(gB + k2, &Bs[nx2 * BUF + wbase]);
      GLDS16(gB + k2 + (size_t)16 * 1024, &Bs[nx2 * BUF + wbase + 16 * 32]);
    }
    {  // compute on buf[cur] (reads bank-conflict-free via kgs)
      const int cb = cur * BUF;
      f16x8 af[4];
#pragma unroll
      for (int mf = 0; mf < 4; ++mf)
        af[mf] = *(const f16x8*)&As[cb + (wm * 64 + mf * 16 + lr) * 32 + kgs];
#pragma unroll
      for (int nf = 0; nf < 4; ++nf) {
        f16x8 bf = *(const f16x8*)&Bs[cb + (wn * 64 + nf * 16 + lr) * 32 + kgs];
#pragma unroll
        for (int mf = 0; mf < 4; ++mf) acc[mf][nf] = MFMA_F16(af[mf], bf, acc[mf][nf]);
      }
    }
    if (step + 1 < 32) {
      SCHED_FENCE();  // pin this step's ds_read+MFMA above the wait/barrier
      if (step + 2 < 32) VMCNT4();  // tile step+1 landed; step+2's 4 loads in flight
      else               VMCNT0();  // nothing left in flight to hide behind
      __builtin_amdgcn_s_barrier();
      SCHED_FENCE();  // pin next step below the barrier
    }
    cur = cur + 1; if (cur >= 3) cur -= 3;
  }

  if (MODE == 0) {
#pragma unroll
    for (int nf = 0; nf < 4; ++nf) {
      int col = n0 + wn * 64 + nf * 16 + (l & 15);
      int which = col >> 10;            // wave-uniform: 0:q 1:k 2:v
      int rem = col & 1023;
      int h = rem >> 6, d = rem & 63;
      int fi = d >> 1;
      float sc = (which == 0) ? QSCALE : 1.0f;
#pragma unroll
      for (int mf = 0; mf < 4; ++mf) {
#pragma unroll
        for (int r = 0; r < 4; ++r) {
          int row = m0 + wm * 64 + mf * 16 + (l >> 4) * 4 + r;
          int bbo = row >> 12, n = row & 4095;
          size_t idx = ((size_t)(bbo * NH + h) * NTOK + n) * HD + d;
          float val = acc[mf][nf][r];
          if (which == 2) {
            vd[idx] = f2h(val);
          } else {
            float par = __shfl_xor(val, 1);
            float cc = ct[n * 32 + fi], ss = st[n * 32 + fi];
            float a0 = val * sc, a1 = par * sc;
            float o = (d & 1) ? fmaf(a0, cc, a1 * ss) : fmaf(a0, cc, -(a1 * ss));
            ((which == 0) ? qd : kd)[idx] = (u16)f2bf(o);
          }
        }
      }
    }
  } else {
#pragma unroll
    for (int nf = 0; nf < 4; ++nf) {
      int col = n0 + wn * 64 + nf * 16 + (l & 15);
      float bl_ = bias[col];
#pragma unroll
      for (int mf = 0; mf < 4; ++mf) {
#pragma unroll
        for (int r = 0; r < 4; ++r) {
          int row = m0 + wm * 64 + mf * 16 + (l >> 4) * 4 + r;
          C[(size_t)row * 1024 + col] = acc[mf][nf][r] + bl_;
        }
      }
    }
  }
}

// ---------------- MFMA block attention with on-the-fly coarsening (unchanged) ----------------
#define KP 72   // K LDS pitch (bf16)
#define VP 136  // V^T LDS pitch (fp16)
#define PP 136  // P LDS pitch (fp16)
template <int LV, int FINE>
__global__ __launch_bounds__(256, 2) void attn_mfma_kernel(
    const u16* __restrict__ qg, const u16* __restrict__ kgl, const u16* __restrict__ vg,
    float* __restrict__ yl, float* __restrict__ al) {
  constexpr int R = 1 << LV;
  constexpr float QKSC = 1.0f / (float)R;
  __shared__ __align__(16) u16 Ks[128 * KP];
  __shared__ __align__(16) u16 Vt[64 * VP];
  __shared__ __align__(16) u16 Ps[128 * PP];
  const int t = threadIdx.x;
  const int blk = blockIdx.x, bh = blockIdx.y;
  const int l = t & 63, w = t >> 6;
  const int lr = l & 15, lg = l >> 4;
  const int nl = NTOK >> LV;
  const size_t bbase = (size_t)bh * NTOK;

  s16x8 aq[2][2];
#pragma unroll
  for (int mf = 0; mf < 2; ++mf)
#pragma unroll
    for (int ks = 0; ks < 2; ++ks) {
      int qrow = blk * 128 + w * 32 + mf * 16 + lr;
      const u16* src = qg + (bbase + ((size_t)qrow << LV)) * HD + ks * 32 + lg * 8;
      if (LV == 0) {
        aq[mf][ks] = *(const s16x8*)src;
      } else {
        float s[8] = {};
#pragma unroll
        for (int ss = 0; ss < R; ++ss) {
          uint4 a = *(const uint4*)(src + (size_t)ss * HD);
          float f[8];
          up8(a, f);
#pragma unroll
          for (int c = 0; c < 8; ++c) s[c] += f[c];
        }
        union { uint4 u; s16x8 v; } cv;
        cv.u = make_uint4(pk2(s[0] * QKSC, s[1] * QKSC), pk2(s[2] * QKSC, s[3] * QKSC),
                          pk2(s[4] * QKSC, s[5] * QKSC), pk2(s[6] * QKSC, s[7] * QKSC));
        aq[mf][ks] = cv.v;
      }
    }

  f32x4 zero4 = {0.f, 0.f, 0.f, 0.f};
  f32x4 accY[2][4];
  float asum[2][4];
#pragma unroll
  for (int mf = 0; mf < 2; ++mf)
#pragma unroll
    for (int nf = 0; nf < 4; ++nf) accY[mf][nf] = zero4;
#pragma unroll
  for (int mf = 0; mf < 2; ++mf)
#pragma unroll
    for (int r = 0; r < 4; ++r) asum[mf][r] = 0.f;

  const int npass = FINE ? 2 : 1;
  for (int pass = 0; pass < npass; ++pass) {
    const int kblk = (pass == 0) ? (blk ^ 1) : blk;
    __syncthreads();
#pragma unroll
    for (int it = 0; it < 2; ++it) {
      int kk = it * 64 + (t >> 2), dq = (t & 3) * 16;
      const u16* src = kgl + (bbase + (((size_t)kblk * 128 + kk) << LV)) * HD + dq;
      if (LV == 0) {
        *(uint4*)&Ks[kk * KP + dq] = *(const uint4*)src;
        *(uint4*)&Ks[kk * KP + dq + 8] = *(const uint4*)(src + 8);
      } else {
        float s[16] = {};
#pragma unroll
        for (int ss = 0; ss < R; ++ss) {
          float f[8];
          up8(*(const uint4*)(src + (size_t)ss * HD), f);
#pragma unroll
          for (int c = 0; c < 8; ++c) s[c] += f[c];
          up8(*(const uint4*)(src + (size_t)ss * HD + 8), f);
#pragma unroll
          for (int c = 0; c < 8; ++c) s[8 + c] += f[c];
        }
        u32 pk[8];
#pragma unroll
        for (int j = 0; j < 8; ++j) pk[j] = pk2(s[2 * j] * QKSC, s[2 * j + 1] * QKSC);
        *(uint4*)&Ks[kk * KP + dq] = make_uint4(pk[0], pk[1], pk[2], pk[3]);
        *(uint4*)&Ks[kk * KP + dq + 8] = make_uint4(pk[4], pk[5], pk[6], pk[7]);
      }
    }
#pragma unroll
    for (int it = 0; it < 2; ++it) {
      int kk = it * 64 + (t >> 2), dq = (t & 3) * 16;
      const u16* src = vg + (bbase + (((size_t)kblk * 128 + kk) << LV)) * HD + dq;
      u16 hv[16];
      if (LV == 0) {
        union { uint4 u; u16 h[8]; } a0, a1;
        a0.u = *(const uint4*)src;
        a1.u = *(const uint4*)(src + 8);
#pragma unroll
        for (int c = 0; c < 8; ++c) { hv[c] = a0.h[c]; hv[8 + c] = a1.h[c]; }
      } else {
        float s[16] = {};
#pragma unroll
        for (int ss = 0; ss < R; ++ss) {
          float f[8];
          up8h(*(const uint4*)(src + (size_t)ss * HD), f);
#pragma unroll
          for (int c = 0; c < 8; ++c) s[c] += f[c];
          up8h(*(const uint4*)(src + (size_t)ss * HD + 8), f);
#pragma unroll
          for (int c = 0; c < 8; ++c) s[8 + c] += f[c];
        }
#pragma unroll
        for (int c = 0; c < 16; ++c) hv[c] = f2h(s[c]);
      }
#pragma unroll
      for (int c = 0; c < 16; ++c) {
        int dv = dq + c;
        int col = kk ^ (((dv >> 4) & 1) << 5) ^ (((dv >> 5) & 1) << 3);
        Vt[dv * VP + col] = hv[c];
      }
    }
    __syncthreads();
    f32x4 accS[2][8];
#pragma unroll
    for (int mf = 0; mf < 2; ++mf)
#pragma unroll
      for (int nf = 0; nf < 8; ++nf) accS[mf][nf] = zero4;
#pragma unroll
    for (int nf = 0; nf < 8; ++nf)
#pragma unroll
      for (int ks = 0; ks < 2; ++ks) {
        s16x8 bk = *(const s16x8*)&Ks[(nf * 16 + lr) * KP + ks * 32 + lg * 8];
        accS[0][nf] = MFMA_BF16(aq[0][ks], bk, accS[0][nf]);
        accS[1][nf] = MFMA_BF16(aq[1][ks], bk, accS[1][nf]);
      }
#pragma unroll
    for (int mf = 0; mf < 2; ++mf)
#pragma unroll
      for (int r = 0; r < 4; ++r) {
        float m = accS[mf][0][r];
#pragma unroll
        for (int nf = 1; nf < 8; ++nf) m = fmaxf(m, accS[mf][nf][r]);
#pragma unroll
        for (int xm = 1; xm < 16; xm <<= 1) m = fmaxf(m, __shfl_xor(m, xm));
        float s = 0.f;
#pragma unroll
        for (int nf = 0; nf < 8; ++nf) {
          float e = __expf(accS[mf][nf][r] - m);
          accS[mf][nf][r] = e;
          s += e;
        }
#pragma unroll
        for (int xm = 1; xm < 16; xm <<= 1) s += __shfl_xor(s, xm);
        asum[mf][r] += s;
      }
#pragma unroll
    for (int mf = 0; mf < 2; ++mf)
#pragma unroll
      for (int nf = 0; nf < 8; ++nf)
#pragma unroll
        for (int r = 0; r < 4; ++r) {
          int qrow = w * 32 + mf * 16 + lg * 4 + r;
          int col = (nf * 16 + lr) ^ (((qrow >> 3) & 1) << 4);
          Ps[qrow * PP + col] = f2h(accS[mf][nf][r]);
        }
    __syncthreads();
#pragma unroll
    for (int ks4 = 0; ks4 < 4; ++ks4) {
      f16x8 ap[2];
#pragma unroll
      for (int mf = 0; mf < 2; ++mf) {
        int prow = w * 32 + mf * 16 + lr;
        int koff = (ks4 * 32 + lg * 8) ^ (((lr >> 3) & 1) << 4);
        ap[mf] = *(const f16x8*)&Ps[prow * PP + koff];
      }
#pragma unroll
      for (int nf = 0; nf < 4; ++nf) {
        int koff = (ks4 * 32 + lg * 8) ^ ((nf & 1) << 5) ^ (((nf >> 1) & 1) << 3);
        f16x8 bv = *(const f16x8*)&Vt[(nf * 16 + lr) * VP + koff];
        accY[0][nf] = MFMA_F16(ap[0], bv, accY[0][nf]);
        accY[1][nf] = MFMA_F16(ap[1], bv, accY[1][nf]);
      }
    }
  }
#pragma unroll
  for (int mf = 0; mf < 2; ++mf) {
    if (lr == 0) {
#pragma unroll
      for (int r = 0; r < 4; ++r)
        al[(size_t)bh * nl + blk * 128 + w * 32 + mf * 16 + lg * 4 + r] = asum[mf][r];
    }
#pragma unroll
    for (int nf = 0; nf < 4; ++nf)
#pragma unroll
      for (int r = 0; r < 4; ++r) {
        int qrow = blk * 128 + w * 32 + mf * 16 + lg * 4 + r;
        yl[((size_t)bh * nl + qrow) * HD + nf * 16 + lr] = accY[mf][nf][r];
      }
  }
}

// ---------------- pyramid combine ----------------
__global__ __launch_bounds__(256) void combine_pyr_kernel(
    const float* __restrict__ Yf, const float* __restrict__ Y1, const float* __restrict__ Y2,
    const float* __restrict__ Y3, const float* __restrict__ Y4,
    const float* __restrict__ Af, const float* __restrict__ A1, const float* __restrict__ A2,
    const float* __restrict__ A3, const float* __restrict__ A4, u16* __restrict__ out) {
  int row = blockIdx.x, t = threadIdx.x;  // row = b*4096 + tok
  int b = row >> 12, tok = row & 4095;
  int h = t >> 4, d = (t & 15) * 4;
  int bh = b * NH + h;
  float a = Af[(size_t)bh * 4096 + tok] + A1[(size_t)bh * 2048 + (tok >> 1)] +
            A2[(size_t)bh * 1024 + (tok >> 2)] + A3[(size_t)bh * 512 + (tok >> 3)] +
            A4[(size_t)bh * 256 + (tok >> 4)] + 1e-8f;
  float4 y0 = *(const float4*)&Yf[((size_t)bh * 4096 + tok) * HD + d];
  float4 y1 = *(const float4*)&Y1[((size_t)bh * 2048 + (tok >> 1)) * HD + d];
  float4 y2 = *(const float4*)&Y2[((size_t)bh * 1024 + (tok >> 2)) * HD + d];
  float4 y3 = *(const float4*)&Y3[((size_t)bh * 512 + (tok >> 3)) * HD + d];
  float4 y4 = *(const float4*)&Y4[((size_t)bh * 256 + (tok >> 4)) * HD + d];
  float inv = 1.0f / a;
  float o0 = (y0.x + y1.x + y2.x + y3.x + y4.x) * inv;
  float o1 = (y0.y + y1.y + y2.y + y3.y + y4.y) * inv;
  float o2 = (y0.z + y1.z + y2.z + y3.z + y4.z) * inv;
  float o3 = (y0.w + y1.w + y2.w + y3.w + y4.w) * inv;
  *(uint2*)&out[(size_t)row * HID + t * 4] = make_uint2(pkh2(o0, o1), pkh2(o2, o3));
}

extern "C" void kernel_launch(void* const* d_in, const int* in_sizes, int n_in,
                              void* d_out, int out_size, void* d_ws, size_t ws_size,
                              hipStream_t stream) {
  (void)in_sizes; (void)n_in;
  const float* hs = (const float*)d_in[0];
  const float* gm = (const float*)d_in[1];
  const float* bt = (const float*)d_in[2];
  const float* wqkv = (const float*)d_in[3];
  const float* wout = (const float*)d_in[4];
  const float* bout = (const float*)d_in[5];
  float* out = (float*)d_out;

  const size_t MB = 1024ull * 1024ull;
  unsigned char* base = (unsigned char*)d_ws;
  const size_t need = 232 * MB;
  if (ws_size < need) {  // diagnostic: absmax will read ~ (1000 + ws_MiB)
    fill_kernel<<<(out_size + 255) / 256, 256, 0, stream>>>(out, out_size,
                                                            1000.0f + (float)(ws_size >> 20));
    return;
  }

  u16* Qf = (u16*)(base);                    // 32 MiB bf16 [BH][4096][64]
  u16* Kf = (u16*)(base + 32 * MB);          // 32 MiB bf16
  u16* Vf = (u16*)(base + 64 * MB);          // 32 MiB fp16
  float* YACC = (float*)(base + 96 * MB);    // 64 MiB f32 fine Y
  float* Y1 = (float*)(base + 160 * MB);     // 32 MiB
  float* Y2 = (float*)(base + 192 * MB);     // 16 MiB
  float* Y3 = (float*)(base + 208 * MB);     // 8 MiB
  float* Y4 = (float*)(base + 216 * MB);     // 4 MiB
  float* AACC = (float*)(base + 220 * MB);   // ~2 MiB A pyramid
  float* A1 = AACC + (size_t)BH * 4096;
  float* A2 = A1 + (size_t)BH * 2048;
  float* A3 = A2 + (size_t)BH * 1024;
  float* A4 = A3 + (size_t)BH * 512;
  u16* WQT = (u16*)(base + 223 * MB);        // 6 MiB fp16 [3072][1024]
  u16* WOT = (u16*)(base + 229 * MB);        // 2 MiB fp16 [1024][1024]
  float* CT = (float*)(base + 231 * MB);     // 512 KiB
  float* ST = CT + NTOK * 32;                // 512 KiB
  // overlays (stream-ordered): ALN in YACC region (dead before attn writes YACC);
  // attnout over Qf (dead after attn kernels).
  u16* ALN = (u16*)(base + 96 * MB);         // 32 MiB fp16 [16384][1024]
  u16* ATT = (u16*)(base);                   // 32 MiB fp16 [16384][1024]

  rope_table_kernel<<<(NTOK * 32 + 255) / 256, 256, 0, stream>>>(CT, ST);
  ln_f16_kernel<<<NB * NTOK, 256, 0, stream>>>(hs, gm, bt, ALN);
  prep_w_kernel<<<dim3(48, 16), 256, 0, stream>>>(wqkv, WQT, 3072);
  prep_w_kernel<<<dim3(16, 16), 256, 0, stream>>>(wout, WOT, 1024);

  gemm_f16_kernel<0><<<3072, 256, 0, stream>>>(
      ALN, WQT, Qf, Kf, Vf, CT, ST, nullptr, nullptr, 24);

  attn_mfma_kernel<0, 1><<<dim3(32, BH), 256, 0, stream>>>(Qf, Kf, Vf, YACC, AACC);
  attn_mfma_kernel<1, 0><<<dim3(16, BH), 256, 0, stream>>>(Qf, Kf, Vf, Y1, A1);
  attn_mfma_kernel<2, 0><<<dim3(8, BH), 256, 0, stream>>>(Qf, Kf, Vf, Y2, A2);
  attn_mfma_kernel<3, 0><<<dim3(4, BH), 256, 0, stream>>>(Qf, Kf, Vf, Y3, A3);
  attn_mfma_kernel<4, 0><<<dim3(2, BH), 256, 0, stream>>>(Qf, Kf, Vf, Y4, A4);

  combine_pyr_kernel<<<NB * NTOK, 256, 0, stream>>>(YACC, Y1, Y2, Y3, Y4,
                                                    AACC, A1, A2, A3, A4, ATT);
  gemm_f16_kernel<1><<<1024, 256, 0, stream>>>(
      ATT, WOT, nullptr, nullptr, nullptr, nullptr, nullptr, bout, out, 8);
}

// Round 14
// 540.130 us; speedup vs baseline: 1.1494x; 1.0402x over previous
//
#include <hip/hip_runtime.h>
#include <math.h>

#define NTOK 4096
#define NB 4
#define NH 16
#define HD 64
#define HID 1024
#define BH 64          // NB*NH
#define QSCALE 0.125f  // 64^-0.5

typedef unsigned short u16;
typedef unsigned int u32;
typedef __attribute__((ext_vector_type(8))) _Float16 f16x8;
typedef __attribute__((ext_vector_type(8))) short s16x8;
typedef __attribute__((ext_vector_type(4))) float f32x4;
#define MFMA_F16(a, b, c) __builtin_amdgcn_mfma_f32_16x16x32_f16(a, b, c, 0, 0, 0)
#define MFMA_BF16(a, b, c) __builtin_amdgcn_mfma_f32_16x16x32_bf16(a, b, c, 0, 0, 0)
// async global -> LDS, 16B per lane, dest = wave-uniform base + lane*16
#define GLDS16(gptr, lptr)                                                          \
  __builtin_amdgcn_global_load_lds(                                                \
      (const __attribute__((address_space(1))) void*)(gptr),                       \
      (__attribute__((address_space(3))) void*)(lptr), 16, 0, 0)
#define VMCNT0() asm volatile("s_waitcnt vmcnt(0)" ::: "memory")
#define VMCNT4() asm volatile("s_waitcnt vmcnt(4)" ::: "memory")
#define SCHED_FENCE() __builtin_amdgcn_sched_barrier(0)

__device__ __forceinline__ float bf2f(u32 u) {
  union { u32 i; float f; } x; x.i = u << 16; return x.f;
}
__device__ __forceinline__ u32 f2bf(float f) {
  union { float f; u32 i; } x; x.f = f;
  return (x.i + 0x7fffu + ((x.i >> 16) & 1u)) >> 16;  // RTNE
}
__device__ __forceinline__ u32 pk2(float a, float b) {
  return f2bf(a) | (f2bf(b) << 16);
}
__device__ __forceinline__ u32 pkh2(float a, float b) {  // 2 x f32 -> packed fp16
  _Float16 ha = (_Float16)a, hb = (_Float16)b;
  u16 x, y;
  __builtin_memcpy(&x, &ha, 2);
  __builtin_memcpy(&y, &hb, 2);
  return (u32)x | ((u32)y << 16);
}
__device__ __forceinline__ u16 f2h(float a) {
  _Float16 h = (_Float16)a;
  u16 x;
  __builtin_memcpy(&x, &h, 2);
  return x;
}
__device__ __forceinline__ void up8(uint4 a, float* f) {  // 8 bf16 -> f32
  f[0] = bf2f(a.x & 0xffffu); f[1] = bf2f(a.x >> 16);
  f[2] = bf2f(a.y & 0xffffu); f[3] = bf2f(a.y >> 16);
  f[4] = bf2f(a.z & 0xffffu); f[5] = bf2f(a.z >> 16);
  f[6] = bf2f(a.w & 0xffffu); f[7] = bf2f(a.w >> 16);
}
__device__ __forceinline__ void up8h(uint4 a, float* f) {  // 8 fp16 -> f32
  union { uint4 u; _Float16 h[8]; } x;
  x.u = a;
#pragma unroll
  for (int c = 0; c < 8; ++c) f[c] = (float)x.h[c];
}
__device__ __forceinline__ void up4h(uint2 a, float* f) {  // 4 fp16 -> f32
  union { uint2 u; _Float16 h[4]; } x;
  x.u = a;
#pragma unroll
  for (int c = 0; c < 4; ++c) f[c] = (float)x.h[c];
}

// ---------------- diagnostic fill ----------------
__global__ void fill_kernel(float* __restrict__ out, int n, float v) {
  int i = blockIdx.x * 256 + threadIdx.x;
  if (i < n) out[i] = v;
}

// ---------------- RoPE tables ----------------
__global__ void rope_table_kernel(float* __restrict__ ct, float* __restrict__ st) {
  int idx = blockIdx.x * 256 + threadIdx.x;
  if (idx >= NTOK * 32) return;
  int n = idx >> 5, i = idx & 31;
  float t = powf(10000.0f, (float)(2 * i));   // inf for i>=5 -> inv=0 (matches f64 ~1e-245)
  float inv = 1.0f / (t / 64.0f);
  float f = (float)n * inv;
  ct[idx] = cosf(f);
  st[idx] = sinf(f);
}

// ---------------- LayerNorm -> fp16 ----------------
__global__ __launch_bounds__(256) void ln_f16_kernel(const float* __restrict__ in,
                                                     const float* __restrict__ gm,
                                                     const float* __restrict__ bt,
                                                     u16* __restrict__ out) {
  __shared__ float sh[8];
  int row = blockIdx.x, t = threadIdx.x;
  float4 x = ((const float4*)(in + (size_t)row * HID))[t];
  float s1 = x.x + x.y + x.z + x.w;
  float s2 = x.x * x.x + x.y * x.y + x.z * x.z + x.w * x.w;
#pragma unroll
  for (int o = 32; o > 0; o >>= 1) {
    s1 += __shfl_down(s1, o, 64);
    s2 += __shfl_down(s2, o, 64);
  }
  if ((t & 63) == 0) { sh[t >> 6] = s1; sh[4 + (t >> 6)] = s2; }
  __syncthreads();
  float S1 = sh[0] + sh[1] + sh[2] + sh[3];
  float S2 = sh[4] + sh[5] + sh[6] + sh[7];
  float mu = S1 * (1.0f / HID);
  float var = S2 * (1.0f / HID) - mu * mu;
  float rstd = 1.0f / sqrtf(var + 1e-5f);
  float4 g = ((const float4*)gm)[t], b = ((const float4*)bt)[t];
  float o0 = (x.x - mu) * rstd * g.x + b.x;
  float o1 = (x.y - mu) * rstd * g.y + b.y;
  float o2 = (x.z - mu) * rstd * g.z + b.z;
  float o3 = (x.w - mu) * rstd * g.w + b.w;
  *(uint2*)&out[(size_t)row * HID + t * 4] = make_uint2(pkh2(o0, o1), pkh2(o2, o3));
}

// ---------------- weight prep: w [1024][N] f32 -> w^T fp16 [N][1024] ----------------
__global__ __launch_bounds__(256) void prep_w_kernel(const float* __restrict__ w,
                                                     u16* __restrict__ wt, int N) {
  __shared__ float T[64][65];
  int t = threadIdx.x;
  int n0 = blockIdx.x * 64, k0 = blockIdx.y * 64;
  {
    int k = t >> 2, nc = (t & 3) * 16;
    const float* src = w + (size_t)(k0 + k) * N + n0 + nc;
#pragma unroll
    for (int i = 0; i < 4; ++i) {
      float4 x = *(const float4*)(src + i * 4);
      T[nc + i * 4 + 0][k] = x.x;
      T[nc + i * 4 + 1][k] = x.y;
      T[nc + i * 4 + 2][k] = x.z;
      T[nc + i * 4 + 3][k] = x.w;
    }
  }
  __syncthreads();
  {
    int n = t >> 2, kc = (t & 3) * 16;
    u32 pk[8];
#pragma unroll
    for (int j = 0; j < 8; ++j) pk[j] = pkh2(T[n][kc + 2 * j], T[n][kc + 2 * j + 1]);
    size_t dst = (size_t)(n0 + n) * 1024 + k0 + kc;
    *(uint4*)&wt[dst] = make_uint4(pk[0], pk[1], pk[2], pk[3]);
    *(uint4*)&wt[dst + 8] = make_uint4(pk[4], pk[5], pk[6], pk[7]);
  }
}

// ---------------- V transpose: Vf [bh][tok][dv] fp16 -> VT [bh][dv][tok] ----------------
__global__ __launch_bounds__(256) void transpose_v_kernel(const u16* __restrict__ vf,
                                                          u16* __restrict__ vt) {
  __shared__ u16 T[64][72];
  int bh = blockIdx.y, tok0 = blockIdx.x * 64;
  int t = threadIdx.x;
  {
    int tk = t >> 2, d0 = (t & 3) * 16;
    const u16* src = vf + ((size_t)bh * NTOK + tok0 + tk) * HD + d0;
    *(uint4*)&T[tk][d0] = *(const uint4*)src;
    *(uint4*)&T[tk][d0 + 8] = *(const uint4*)(src + 8);
  }
  __syncthreads();
  {
    int dv = t >> 2, k0 = (t & 3) * 16;
    union { u16 v[16]; uint4 q[2]; } o;
#pragma unroll
    for (int i = 0; i < 16; ++i) o.v[i] = T[k0 + i][dv];
    u16* dst = vt + ((size_t)bh * HD + dv) * NTOK + tok0 + k0;
    *(uint4*)dst = o.q[0];
    *(uint4*)(dst + 8) = o.q[1];
  }
}

// ---------------- fp16 MFMA GEMM (unchanged from passing round 13) ----------------
template <int MODE>
__global__ __launch_bounds__(256) void gemm_f16_kernel(
    const u16* __restrict__ At, const u16* __restrict__ Bt,
    u16* __restrict__ qd, u16* __restrict__ kd, u16* __restrict__ vd,
    const float* __restrict__ ct, const float* __restrict__ st,
    const float* __restrict__ bias, float* __restrict__ C, int nxb) {
  constexpr int BUF = 128 * 32;  // u16 per buffer
  __shared__ __align__(16) u16 As[3 * BUF], Bs[3 * BUF];
  const int t = threadIdx.x;
  const int nwg = gridDim.x;
  const int bid = blockIdx.x;
  const int wid = (bid & 7) * (nwg >> 3) + (bid >> 3);
  const int m0 = (wid / nxb) * 128, n0 = (wid % nxb) * 128;
  const int l = t & 63, w = t >> 6;
  const int wm = w & 1, wn = w >> 1;
  const int lr = l & 15;
  const int kgs = (((l >> 4) ^ ((lr >> 1) & 3))) * 8;

  const int schunk = (l & 3) ^ ((l >> 3) & 3);
  const u16* gA = At + (size_t)(m0 + w * 32 + (l >> 2)) * 1024 + schunk * 8;
  const u16* gB = Bt + (size_t)(n0 + w * 32 + (l >> 2)) * 1024 + schunk * 8;
  const int wbase = (w * 32) * 32;

  f32x4 zero4 = {0.f, 0.f, 0.f, 0.f};
  f32x4 acc[4][4];
#pragma unroll
  for (int mf = 0; mf < 4; ++mf)
#pragma unroll
    for (int nf = 0; nf < 4; ++nf) acc[mf][nf] = zero4;

  GLDS16(gA, &As[wbase]);
  GLDS16(gA + (size_t)16 * 1024, &As[wbase + 16 * 32]);
  GLDS16(gB, &Bs[wbase]);
  GLDS16(gB + (size_t)16 * 1024, &Bs[wbase + 16 * 32]);
  GLDS16(gA + 32, &As[BUF + wbase]);
  GLDS16(gA + 32 + (size_t)16 * 1024, &As[BUF + wbase + 16 * 32]);
  GLDS16(gB + 32, &Bs[BUF + wbase]);
  GLDS16(gB + 32 + (size_t)16 * 1024, &Bs[BUF + wbase + 16 * 32]);
  VMCNT4();
  __builtin_amdgcn_s_barrier();
  SCHED_FENCE();

  int cur = 0;
  for (int step = 0; step < 32; ++step) {
    int nx2 = cur + 2; if (nx2 >= 3) nx2 -= 3;
    if (step + 2 < 32) {
      int k2 = (step + 2) * 32;
      GLDS16(gA + k2, &As[nx2 * BUF + wbase]);
      GLDS16(gA + k2 + (size_t)16 * 1024, &As[nx2 * BUF + wbase + 16 * 32]);
      GLDS16(gB + k2, &Bs[nx2 * BUF + wbase]);
      GLDS16(gB + k2 + (size_t)16 * 1024, &Bs[nx2 * BUF + wbase + 16 * 32]);
    }
    {
      const int cb = cur * BUF;
      f16x8 af[4];
#pragma unroll
      for (int mf = 0; mf < 4; ++mf)
        af[mf] = *(const f16x8*)&As[cb + (wm * 64 + mf * 16 + lr) * 32 + kgs];
#pragma unroll
      for (int nf = 0; nf < 4; ++nf) {
        f16x8 bf = *(const f16x8*)&Bs[cb + (wn * 64 + nf * 16 + lr) * 32 + kgs];
#pragma unroll
        for (int mf = 0; mf < 4; ++mf) acc[mf][nf] = MFMA_F16(af[mf], bf, acc[mf][nf]);
      }
    }
    if (step + 1 < 32) {
      SCHED_FENCE();
      if (step + 2 < 32) VMCNT4();
      else               VMCNT0();
      __builtin_amdgcn_s_barrier();
      SCHED_FENCE();
    }
    cur = cur + 1; if (cur >= 3) cur -= 3;
  }

  if (MODE == 0) {
#pragma unroll
    for (int nf = 0; nf < 4; ++nf) {
      int col = n0 + wn * 64 + nf * 16 + (l & 15);
      int which = col >> 10;
      int rem = col & 1023;
      int h = rem >> 6, d = rem & 63;
      int fi = d >> 1;
      float sc = (which == 0) ? QSCALE : 1.0f;
#pragma unroll
      for (int mf = 0; mf < 4; ++mf) {
#pragma unroll
        for (int r = 0; r < 4; ++r) {
          int row = m0 + wm * 64 + mf * 16 + (l >> 4) * 4 + r;
          int bbo = row >> 12, n = row & 4095;
          size_t idx = ((size_t)(bbo * NH + h) * NTOK + n) * HD + d;
          float val = acc[mf][nf][r];
          if (which == 2) {
            vd[idx] = f2h(val);
          } else {
            float par = __shfl_xor(val, 1);
            float cc = ct[n * 32 + fi], ss = st[n * 32 + fi];
            float a0 = val * sc, a1 = par * sc;
            float o = (d & 1) ? fmaf(a0, cc, a1 * ss) : fmaf(a0, cc, -(a1 * ss));
            ((which == 0) ? qd : kd)[idx] = (u16)f2bf(o);
          }
        }
      }
    }
  } else {
#pragma unroll
    for (int nf = 0; nf < 4; ++nf) {
      int col = n0 + wn * 64 + nf * 16 + (l & 15);
      float bl_ = bias[col];
#pragma unroll
      for (int mf = 0; mf < 4; ++mf) {
#pragma unroll
        for (int r = 0; r < 4; ++r) {
          int row = m0 + wm * 64 + mf * 16 + (l >> 4) * 4 + r;
          C[(size_t)row * 1024 + col] = acc[mf][nf][r] + bl_;
        }
      }
    }
  }
}

// ---------------- MFMA block attention, swapped-operand orientation ----------------
// S^T = K·Q^T (A=K rows, B=Q^T cols)  ->  lane holds k=kf*16+lg*4+r, q=qf*16+lr.
// P[q][k] stored with packed b64 writes; PV: Y^T = V^T·P^T (A=Vt rows, B=P rows).
// V comes pre-transposed from global VT[bh][dv][tok].
#define KP 72   // K LDS pitch (bf16)
#define VP 136  // V^T LDS pitch (fp16)
#define PP 136  // P LDS pitch (fp16)
template <int LV, int FINE>
__global__ __launch_bounds__(256, 2) void attn_mfma_kernel(
    const u16* __restrict__ qg, const u16* __restrict__ kgl, const u16* __restrict__ vtg,
    u16* __restrict__ yl, float* __restrict__ al) {
  constexpr int R = 1 << LV;
  constexpr float QKSC = 1.0f / (float)R;
  __shared__ __align__(16) u16 Ks[128 * KP];
  __shared__ __align__(16) u16 Vt[64 * VP];
  __shared__ __align__(16) u16 Ps[128 * PP];
  const int t = threadIdx.x;
  const int blk = blockIdx.x, bh = blockIdx.y;
  const int l = t & 63, w = t >> 6;
  const int lr = l & 15, lg = l >> 4;
  const int nl = NTOK >> LV;
  const size_t bbase = (size_t)bh * NTOK;

  // Q fragments (B-operand: lane lr = q-col), wave w owns q rows [32w, 32w+32)
  s16x8 aq[2][2];
#pragma unroll
  for (int qf = 0; qf < 2; ++qf)
#pragma unroll
    for (int ks = 0; ks < 2; ++ks) {
      int qrow = blk * 128 + w * 32 + qf * 16 + lr;
      const u16* src = qg + (bbase + ((size_t)qrow << LV)) * HD + ks * 32 + lg * 8;
      if (LV == 0) {
        aq[qf][ks] = *(const s16x8*)src;
      } else {
        float s[8] = {};
#pragma unroll
        for (int ss = 0; ss < R; ++ss) {
          uint4 a = *(const uint4*)(src + (size_t)ss * HD);
          float f[8];
          up8(a, f);
#pragma unroll
          for (int c = 0; c < 8; ++c) s[c] += f[c];
        }
        union { uint4 u; s16x8 v; } cv;
        cv.u = make_uint4(pk2(s[0] * QKSC, s[1] * QKSC), pk2(s[2] * QKSC, s[3] * QKSC),
                          pk2(s[4] * QKSC, s[5] * QKSC), pk2(s[6] * QKSC, s[7] * QKSC));
        aq[qf][ks] = cv.v;
      }
    }

  f32x4 zero4 = {0.f, 0.f, 0.f, 0.f};
  f32x4 accYT[4][2];  // [dvf][qf]; lane: q = qf*16+lr, dv = dvf*16+lg*4+r
  float asum[2] = {0.f, 0.f};
#pragma unroll
  for (int dvf = 0; dvf < 4; ++dvf)
#pragma unroll
    for (int qf = 0; qf < 2; ++qf) accYT[dvf][qf] = zero4;

  const int npass = FINE ? 2 : 1;
  for (int pass = 0; pass < npass; ++pass) {
    const int kblk = (pass == 0) ? (blk ^ 1) : blk;
    __syncthreads();  // prev pass's LDS readers done
    // ---- stage K [k][d] bf16 (coarse mean)
#pragma unroll
    for (int it = 0; it < 2; ++it) {
      int kk = it * 64 + (t >> 2), dq = (t & 3) * 16;
      const u16* src = kgl + (bbase + (((size_t)kblk * 128 + kk) << LV)) * HD + dq;
      if (LV == 0) {
        *(uint4*)&Ks[kk * KP + dq] = *(const uint4*)src;
        *(uint4*)&Ks[kk * KP + dq + 8] = *(const uint4*)(src + 8);
      } else {
        float s[16] = {};
#pragma unroll
        for (int ss = 0; ss < R; ++ss) {
          float f[8];
          up8(*(const uint4*)(src + (size_t)ss * HD), f);
#pragma unroll
          for (int c = 0; c < 8; ++c) s[c] += f[c];
          up8(*(const uint4*)(src + (size_t)ss * HD + 8), f);
#pragma unroll
          for (int c = 0; c < 8; ++c) s[8 + c] += f[c];
        }
        u32 pk[8];
#pragma unroll
        for (int j = 0; j < 8; ++j) pk[j] = pk2(s[2 * j] * QKSC, s[2 * j + 1] * QKSC);
        *(uint4*)&Ks[kk * KP + dq] = make_uint4(pk[0], pk[1], pk[2], pk[3]);
        *(uint4*)&Ks[kk * KP + dq + 8] = make_uint4(pk[4], pk[5], pk[6], pk[7]);
      }
    }
    // ---- stage V^T [dv][k] fp16 from global VT (vector copies / vector sums)
    {
      int dv = t >> 2, j0 = (t & 3) * 32;
      const u16* src = vtg + ((size_t)bh * HD + dv) * NTOK +
                       (((size_t)(kblk * 128 + j0)) << LV);
      if (LV == 0) {
#pragma unroll
        for (int c = 0; c < 4; ++c)
          *(uint4*)&Vt[dv * VP + j0 + c * 8] = *(const uint4*)(src + c * 8);
      } else {
        float acc[32];
#pragma unroll
        for (int j = 0; j < 32; ++j) acc[j] = 0.f;
#pragma unroll
        for (int c = 0; c < 4 * R; ++c) {
          float f[8];
          up8h(*(const uint4*)(src + c * 8), f);
#pragma unroll
          for (int e = 0; e < 8; ++e) acc[(c * 8 + e) >> LV] += f[e];
        }
#pragma unroll
        for (int j = 0; j < 32; j += 8) {
          uint4 pkv;
          pkv.x = pkh2(acc[j + 0], acc[j + 1]);
          pkv.y = pkh2(acc[j + 2], acc[j + 3]);
          pkv.z = pkh2(acc[j + 4], acc[j + 5]);
          pkv.w = pkh2(acc[j + 6], acc[j + 7]);
          *(uint4*)&Vt[dv * VP + j0 + j] = pkv;
        }
      }
    }
    __syncthreads();
    // ---- QK^T (swapped): accST[kf][qf], D col=q, row=k
    f32x4 accST[8][2];
#pragma unroll
    for (int kf = 0; kf < 8; ++kf)
#pragma unroll
      for (int qf = 0; qf < 2; ++qf) accST[kf][qf] = zero4;
#pragma unroll
    for (int kf = 0; kf < 8; ++kf)
#pragma unroll
      for (int ks = 0; ks < 2; ++ks) {
        s16x8 ak = *(const s16x8*)&Ks[(kf * 16 + lr) * KP + ks * 32 + lg * 8];
        accST[kf][0] = MFMA_BF16(ak, aq[0][ks], accST[kf][0]);
        accST[kf][1] = MFMA_BF16(ak, aq[1][ks], accST[kf][1]);
      }
    // ---- softmax per q (lane holds 32 k-values; reduce over lg via 2 shuffles)
#pragma unroll
    for (int qf = 0; qf < 2; ++qf) {
      float m = accST[0][qf][0];
#pragma unroll
      for (int kf = 0; kf < 8; ++kf)
#pragma unroll
        for (int r = 0; r < 4; ++r) m = fmaxf(m, accST[kf][qf][r]);
      m = fmaxf(m, __shfl_xor(m, 16));
      m = fmaxf(m, __shfl_xor(m, 32));
      float s = 0.f;
#pragma unroll
      for (int kf = 0; kf < 8; ++kf) {
#pragma unroll
        for (int r = 0; r < 4; ++r) {
          float e = __expf(accST[kf][qf][r] - m);
          accST[kf][qf][r] = e;
          s += e;
        }
      }
      s += __shfl_xor(s, 16);
      s += __shfl_xor(s, 32);
      asum[qf] += s;
      // ---- P store: packed b64 (4 consecutive k per write); wave-private rows
#pragma unroll
      for (int kf = 0; kf < 8; ++kf) {
        uint2 pw;
        pw.x = pkh2(accST[kf][qf][0], accST[kf][qf][1]);
        pw.y = pkh2(accST[kf][qf][2], accST[kf][qf][3]);
        *(uint2*)&Ps[(w * 32 + qf * 16 + lr) * PP + kf * 16 + lg * 4] = pw;
      }
    }
    // ---- PV: Y^T = V^T · P^T (Ps rows wave-private -> no barrier; Vt synced above)
#pragma unroll
    for (int ks4 = 0; ks4 < 4; ++ks4) {
      f16x8 pf[2];
#pragma unroll
      for (int qf = 0; qf < 2; ++qf)
        pf[qf] = *(const f16x8*)&Ps[(w * 32 + qf * 16 + lr) * PP + ks4 * 32 + lg * 8];
#pragma unroll
      for (int dvf = 0; dvf < 4; ++dvf) {
        f16x8 vf = *(const f16x8*)&Vt[(dvf * 16 + lr) * VP + ks4 * 32 + lg * 8];
        accYT[dvf][0] = MFMA_F16(vf, pf[0], accYT[dvf][0]);
        accYT[dvf][1] = MFMA_F16(vf, pf[1], accYT[dvf][1]);
      }
    }
  }
  // ---- epilogue: A sums (f32) + Y packed fp16 (4 consecutive dv per store)
#pragma unroll
  for (int qf = 0; qf < 2; ++qf) {
    if (lg == 0)
      al[(size_t)bh * nl + blk * 128 + w * 32 + qf * 16 + lr] = asum[qf];
    int q = blk * 128 + w * 32 + qf * 16 + lr;
#pragma unroll
    for (int dvf = 0; dvf < 4; ++dvf) {
      uint2 yw;
      yw.x = pkh2(accYT[dvf][qf][0], accYT[dvf][qf][1]);
      yw.y = pkh2(accYT[dvf][qf][2], accYT[dvf][qf][3]);
      *(uint2*)&yl[((size_t)bh * nl + q) * HD + dvf * 16 + lg * 4] = yw;
    }
  }
}

// ---------------- pyramid combine (fp16 Y inputs) ----------------
__global__ __launch_bounds__(256) void combine_pyr_kernel(
    const u16* __restrict__ Yf, const u16* __restrict__ Y1, const u16* __restrict__ Y2,
    const u16* __restrict__ Y3, const u16* __restrict__ Y4,
    const float* __restrict__ Af, const float* __restrict__ A1, const float* __restrict__ A2,
    const float* __restrict__ A3, const float* __restrict__ A4, u16* __restrict__ out) {
  int row = blockIdx.x, t = threadIdx.x;  // row = b*4096 + tok
  int b = row >> 12, tok = row & 4095;
  int h = t >> 4, d = (t & 15) * 4;
  int bh = b * NH + h;
  float a = Af[(size_t)bh * 4096 + tok] + A1[(size_t)bh * 2048 + (tok >> 1)] +
            A2[(size_t)bh * 1024 + (tok >> 2)] + A3[(size_t)bh * 512 + (tok >> 3)] +
            A4[(size_t)bh * 256 + (tok >> 4)] + 1e-8f;
  float y[4] = {0.f, 0.f, 0.f, 0.f}, f[4];
  up4h(*(const uint2*)&Yf[((size_t)bh * 4096 + tok) * HD + d], f);
#pragma unroll
  for (int c = 0; c < 4; ++c) y[c] += f[c];
  up4h(*(const uint2*)&Y1[((size_t)bh * 2048 + (tok >> 1)) * HD + d], f);
#pragma unroll
  for (int c = 0; c < 4; ++c) y[c] += f[c];
  up4h(*(const uint2*)&Y2[((size_t)bh * 1024 + (tok >> 2)) * HD + d], f);
#pragma unroll
  for (int c = 0; c < 4; ++c) y[c] += f[c];
  up4h(*(const uint2*)&Y3[((size_t)bh * 512 + (tok >> 3)) * HD + d], f);
#pragma unroll
  for (int c = 0; c < 4; ++c) y[c] += f[c];
  up4h(*(const uint2*)&Y4[((size_t)bh * 256 + (tok >> 4)) * HD + d], f);
#pragma unroll
  for (int c = 0; c < 4; ++c) y[c] += f[c];
  float inv = 1.0f / a;
  *(uint2*)&out[(size_t)row * HID + t * 4] =
      make_uint2(pkh2(y[0] * inv, y[1] * inv), pkh2(y[2] * inv, y[3] * inv));
}

extern "C" void kernel_launch(void* const* d_in, const int* in_sizes, int n_in,
                              void* d_out, int out_size, void* d_ws, size_t ws_size,
                              hipStream_t stream) {
  (void)in_sizes; (void)n_in;
  const float* hs = (const float*)d_in[0];
  const float* gm = (const float*)d_in[1];
  const float* bt = (const float*)d_in[2];
  const float* wqkv = (const float*)d_in[3];
  const float* wout = (const float*)d_in[4];
  const float* bout = (const float*)d_in[5];
  float* out = (float*)d_out;

  const size_t MB = 1024ull * 1024ull;
  unsigned char* base = (unsigned char*)d_ws;
  const size_t need = 233 * MB;
  if (ws_size < need) {  // diagnostic: absmax will read ~ (1000 + ws_MiB)
    fill_kernel<<<(out_size + 255) / 256, 256, 0, stream>>>(out, out_size,
                                                            1000.0f + (float)(ws_size >> 20));
    return;
  }

  u16* Qf = (u16*)(base);                    // 32 MiB bf16 [BH][4096][64]
  u16* Kf = (u16*)(base + 32 * MB);          // 32 MiB bf16
  u16* Vf = (u16*)(base + 64 * MB);          // 32 MiB fp16 [bh][tok][dv]
  u16* Yf = (u16*)(base + 96 * MB);          // 32 MiB fp16 fine Y
  u16* VT = (u16*)(base + 128 * MB);         // 32 MiB fp16 [bh][dv][tok]
  u16* Y1 = (u16*)(base + 160 * MB);         // 16 MiB
  u16* Y2 = (u16*)(base + 176 * MB);         // 8 MiB
  u16* Y3 = (u16*)(base + 184 * MB);         // 4 MiB
  u16* Y4 = (u16*)(base + 188 * MB);         // 2 MiB
  float* AACC = (float*)(base + 190 * MB);   // ~2 MiB A pyramid (f32)
  float* A1 = AACC + (size_t)BH * 4096;
  float* A2 = A1 + (size_t)BH * 2048;
  float* A3 = A2 + (size_t)BH * 1024;
  float* A4 = A3 + (size_t)BH * 512;
  u16* WQT = (u16*)(base + 192 * MB);        // 6 MiB fp16 [3072][1024]
  u16* WOT = (u16*)(base + 198 * MB);        // 2 MiB fp16 [1024][1024]
  float* CT = (float*)(base + 200 * MB);     // 512 KiB
  float* ST = CT + NTOK * 32;                // 512 KiB
  u16* ALN = (u16*)(base + 201 * MB);        // 32 MiB fp16 [16384][1024]
  u16* ATT = (u16*)(base);                   // overlays Qf (dead after attn)

  rope_table_kernel<<<(NTOK * 32 + 255) / 256, 256, 0, stream>>>(CT, ST);
  ln_f16_kernel<<<NB * NTOK, 256, 0, stream>>>(hs, gm, bt, ALN);
  prep_w_kernel<<<dim3(48, 16), 256, 0, stream>>>(wqkv, WQT, 3072);
  prep_w_kernel<<<dim3(16, 16), 256, 0, stream>>>(wout, WOT, 1024);

  gemm_f16_kernel<0><<<3072, 256, 0, stream>>>(
      ALN, WQT, Qf, Kf, Vf, CT, ST, nullptr, nullptr, 24);
  transpose_v_kernel<<<dim3(NTOK / 64, BH), 256, 0, stream>>>(Vf, VT);

  attn_mfma_kernel<0, 1><<<dim3(32, BH), 256, 0, stream>>>(Qf, Kf, VT, Yf, AACC);
  attn_mfma_kernel<1, 0><<<dim3(16, BH), 256, 0, stream>>>(Qf, Kf, VT, Y1, A1);
  attn_mfma_kernel<2, 0><<<dim3(8, BH), 256, 0, stream>>>(Qf, Kf, VT, Y2, A2);
  attn_mfma_kernel<3, 0><<<dim3(4, BH), 256, 0, stream>>>(Qf, Kf, VT, Y3, A3);
  attn_mfma_kernel<4, 0><<<dim3(2, BH), 256, 0, stream>>>(Qf, Kf, VT, Y4, A4);

  combine_pyr_kernel<<<NB * NTOK, 256, 0, stream>>>(Yf, Y1, Y2, Y3, Y4,
                                                    AACC, A1, A2, A3, A4, ATT);
  gemm_f16_kernel<1><<<1024, 256, 0, stream>>>(
      ATT, WOT, nullptr, nullptr, nullptr, nullptr, nullptr, bout, out, 8);
}

// Round 15
// 476.003 us; speedup vs baseline: 1.3042x; 1.1347x over previous
//
#include <hip/hip_runtime.h>
#include <math.h>

#define NTOK 4096
#define NB 4
#define NH 16
#define HD 64
#define HID 1024
#define BH 64          // NB*NH
#define QSCALE 0.125f  // 64^-0.5

typedef unsigned short u16;
typedef unsigned int u32;
typedef __attribute__((ext_vector_type(8))) _Float16 f16x8;
typedef __attribute__((ext_vector_type(8))) short s16x8;
typedef __attribute__((ext_vector_type(4))) float f32x4;
#define MFMA_F16(a, b, c) __builtin_amdgcn_mfma_f32_16x16x32_f16(a, b, c, 0, 0, 0)
#define MFMA_BF16(a, b, c) __builtin_amdgcn_mfma_f32_16x16x32_bf16(a, b, c, 0, 0, 0)
// async global -> LDS, 16B per lane, dest = wave-uniform base + lane*16
#define GLDS16(gptr, lptr)                                                          \
  __builtin_amdgcn_global_load_lds(                                                \
      (const __attribute__((address_space(1))) void*)(gptr),                       \
      (__attribute__((address_space(3))) void*)(lptr), 16, 0, 0)
#define VMCNT0() asm volatile("s_waitcnt vmcnt(0)" ::: "memory")
#define VMCNT2() asm volatile("s_waitcnt vmcnt(2)" ::: "memory")
#define SCHED_FENCE() __builtin_amdgcn_sched_barrier(0)

__device__ __forceinline__ float bf2f(u32 u) {
  union { u32 i; float f; } x; x.i = u << 16; return x.f;
}
__device__ __forceinline__ u32 f2bf(float f) {
  union { float f; u32 i; } x; x.f = f;
  return (x.i + 0x7fffu + ((x.i >> 16) & 1u)) >> 16;  // RTNE
}
__device__ __forceinline__ u32 pk2(float a, float b) {
  return f2bf(a) | (f2bf(b) << 16);
}
__device__ __forceinline__ u32 pkh2(float a, float b) {  // 2 x f32 -> packed fp16
  _Float16 ha = (_Float16)a, hb = (_Float16)b;
  u16 x, y;
  __builtin_memcpy(&x, &ha, 2);
  __builtin_memcpy(&y, &hb, 2);
  return (u32)x | ((u32)y << 16);
}
__device__ __forceinline__ u16 f2h(float a) {
  _Float16 h = (_Float16)a;
  u16 x;
  __builtin_memcpy(&x, &h, 2);
  return x;
}
__device__ __forceinline__ void up8(uint4 a, float* f) {  // 8 bf16 -> f32
  f[0] = bf2f(a.x & 0xffffu); f[1] = bf2f(a.x >> 16);
  f[2] = bf2f(a.y & 0xffffu); f[3] = bf2f(a.y >> 16);
  f[4] = bf2f(a.z & 0xffffu); f[5] = bf2f(a.z >> 16);
  f[6] = bf2f(a.w & 0xffffu); f[7] = bf2f(a.w >> 16);
}
__device__ __forceinline__ void up8h(uint4 a, float* f) {  // 8 fp16 -> f32
  union { uint4 u; _Float16 h[8]; } x;
  x.u = a;
#pragma unroll
  for (int c = 0; c < 8; ++c) f[c] = (float)x.h[c];
}
__device__ __forceinline__ void up4h(uint2 a, float* f) {  // 4 fp16 -> f32
  union { uint2 u; _Float16 h[4]; } x;
  x.u = a;
#pragma unroll
  for (int c = 0; c < 4; ++c) f[c] = (float)x.h[c];
}

// ---------------- diagnostic fill ----------------
__global__ void fill_kernel(float* __restrict__ out, int n, float v) {
  int i = blockIdx.x * 256 + threadIdx.x;
  if (i < n) out[i] = v;
}

// ---------------- RoPE tables ----------------
__global__ void rope_table_kernel(float* __restrict__ ct, float* __restrict__ st) {
  int idx = blockIdx.x * 256 + threadIdx.x;
  if (idx >= NTOK * 32) return;
  int n = idx >> 5, i = idx & 31;
  float t = powf(10000.0f, (float)(2 * i));   // inf for i>=5 -> inv=0 (matches f64 ~1e-245)
  float inv = 1.0f / (t / 64.0f);
  float f = (float)n * inv;
  ct[idx] = cosf(f);
  st[idx] = sinf(f);
}

// ---------------- LayerNorm -> fp16 ----------------
__global__ __launch_bounds__(256) void ln_f16_kernel(const float* __restrict__ in,
                                                     const float* __restrict__ gm,
                                                     const float* __restrict__ bt,
                                                     u16* __restrict__ out) {
  __shared__ float sh[8];
  int row = blockIdx.x, t = threadIdx.x;
  float4 x = ((const float4*)(in + (size_t)row * HID))[t];
  float s1 = x.x + x.y + x.z + x.w;
  float s2 = x.x * x.x + x.y * x.y + x.z * x.z + x.w * x.w;
#pragma unroll
  for (int o = 32; o > 0; o >>= 1) {
    s1 += __shfl_down(s1, o, 64);
    s2 += __shfl_down(s2, o, 64);
  }
  if ((t & 63) == 0) { sh[t >> 6] = s1; sh[4 + (t >> 6)] = s2; }
  __syncthreads();
  float S1 = sh[0] + sh[1] + sh[2] + sh[3];
  float S2 = sh[4] + sh[5] + sh[6] + sh[7];
  float mu = S1 * (1.0f / HID);
  float var = S2 * (1.0f / HID) - mu * mu;
  float rstd = 1.0f / sqrtf(var + 1e-5f);
  float4 g = ((const float4*)gm)[t], b = ((const float4*)bt)[t];
  float o0 = (x.x - mu) * rstd * g.x + b.x;
  float o1 = (x.y - mu) * rstd * g.y + b.y;
  float o2 = (x.z - mu) * rstd * g.z + b.z;
  float o3 = (x.w - mu) * rstd * g.w + b.w;
  *(uint2*)&out[(size_t)row * HID + t * 4] = make_uint2(pkh2(o0, o1), pkh2(o2, o3));
}

// ---------------- weight prep: w [1024][N] f32 -> w^T fp16 [N][1024] ----------------
__global__ __launch_bounds__(256) void prep_w_kernel(const float* __restrict__ w,
                                                     u16* __restrict__ wt, int N) {
  __shared__ float T[64][65];
  int t = threadIdx.x;
  int n0 = blockIdx.x * 64, k0 = blockIdx.y * 64;
  {
    int k = t >> 2, nc = (t & 3) * 16;
    const float* src = w + (size_t)(k0 + k) * N + n0 + nc;
#pragma unroll
    for (int i = 0; i < 4; ++i) {
      float4 x = *(const float4*)(src + i * 4);
      T[nc + i * 4 + 0][k] = x.x;
      T[nc + i * 4 + 1][k] = x.y;
      T[nc + i * 4 + 2][k] = x.z;
      T[nc + i * 4 + 3][k] = x.w;
    }
  }
  __syncthreads();
  {
    int n = t >> 2, kc = (t & 3) * 16;
    u32 pk[8];
#pragma unroll
    for (int j = 0; j < 8; ++j) pk[j] = pkh2(T[n][kc + 2 * j], T[n][kc + 2 * j + 1]);
    size_t dst = (size_t)(n0 + n) * 1024 + k0 + kc;
    *(uint4*)&wt[dst] = make_uint4(pk[0], pk[1], pk[2], pk[3]);
    *(uint4*)&wt[dst + 8] = make_uint4(pk[4], pk[5], pk[6], pk[7]);
  }
}

// ---------------- 256x256 fp16 MFMA GEMM, BK=64, 8 waves, deep pipeline ----------------
// 2 K-tile LDS slots (128 KiB). Per K-tile: 1 barrier + 1 counted vmcnt(2).
// Tile j+1's 8 stage-units are issued across tile j's phases (slot (j+1)&1 has no
// readers then). T2 swizzle: physical 16B chunk = logical ^ (row&7) — conflict-free
// ds_read_b128 and unchanged-coalescing pre-swizzled global source.
// MODE 0: LN(hs)@Wqkv epilogue = rope+scatter Q/K bf16, V -> VT fp16 (packed).
// MODE 1: +bias f32 store.
template <int MODE>
__global__ __launch_bounds__(512, 2) void gemm256_kernel(
    const u16* __restrict__ At, const u16* __restrict__ Bt,
    u16* __restrict__ qd, u16* __restrict__ kd, u16* __restrict__ vtd,
    const float* __restrict__ ct, const float* __restrict__ st,
    const float* __restrict__ bias, float* __restrict__ C, int nxb) {
  __shared__ __align__(16) u16 As[2][256 * 64], Bs[2][256 * 64];
  const int t = threadIdx.x;
  const int nwg = gridDim.x, bid = blockIdx.x;
  const int wid = (bid & 7) * (nwg >> 3) + (bid >> 3);  // T1 XCD-chunked remap
  const int m0 = (wid / nxb) * 256, n0 = (wid % nxb) * 256;
  const int l = t & 63, w = t >> 6;       // 8 waves
  const int wm = w >> 2, wn = w & 3;      // 2M x 4N; wave tile 128x64
  const int lr = l & 15, lg = l >> 4;
  const int swr = lr & 7;                 // row-derived xor for frag reads

  // staging: wave w + lane l -> row offset w*8 + (l>>3), source chunk pre-swizzled
  const int swz = (l & 7) ^ (l >> 3);
  const u16* gA = At + (size_t)(m0 + w * 8 + (l >> 3)) * 1024 + swz * 8;
  const u16* gB = Bt + (size_t)(n0 + w * 8 + (l >> 3)) * 1024 + swz * 8;
  const int ldst = (w * 8) * 64;          // wave-uniform LDS base (u16), + a*64*64 per unit

#define STAGE_A(sl, a, kt) GLDS16(gA + (size_t)(a) * 64 * 1024 + (kt) * 64, &As[sl][(a) * 64 * 64 + ldst])
#define STAGE_B(sl, a, kt) GLDS16(gB + (size_t)(a) * 64 * 1024 + (kt) * 64, &Bs[sl][(a) * 64 * 64 + ldst])

  f32x4 zero4 = {0.f, 0.f, 0.f, 0.f};
  f32x4 acc[8][4];
#pragma unroll
  for (int mf = 0; mf < 8; ++mf)
#pragma unroll
    for (int nf = 0; nf < 4; ++nf) acc[mf][nf] = zero4;

  // prologue: stage K-tile 0 -> slot 0 (8 units/wave)
#pragma unroll
  for (int a = 0; a < 4; ++a) { STAGE_A(0, a, 0); STAGE_B(0, a, 0); }

#pragma unroll 2
  for (int j = 0; j < 16; ++j) {
    const int slot = j & 1, nsl = slot ^ 1;
    __builtin_amdgcn_s_barrier();   // all waves done reading tile j-1 (slot nsl)
    if (j + 1 < 16) { STAGE_A(nsl, 0, j + 1); STAGE_B(nsl, 0, j + 1); }
    if (j + 1 < 16) VMCNT2();       // tile j's 8 loads landed; 2 of j+1 in flight
    else           VMCNT0();
    SCHED_FENCE();
    // B fragments for the whole tile (held across phases)
    f16x8 bf[4][2];
#pragma unroll
    for (int nf = 0; nf < 4; ++nf)
#pragma unroll
      for (int ks = 0; ks < 2; ++ks)
        bf[nf][ks] = *(const f16x8*)&Bs[slot][(wn * 64 + nf * 16 + lr) * 64 +
                                             (((ks << 2) + lg) ^ swr) * 8];
    // 4 phases by mf-pairs; issue remaining units of tile j+1 along the way
#pragma unroll
    for (int q = 0; q < 4; ++q) {
      if (j + 1 < 16 && q < 3) { STAGE_A(nsl, q + 1, j + 1); STAGE_B(nsl, q + 1, j + 1); }
      f16x8 af[2][2];
#pragma unroll
      for (int mm = 0; mm < 2; ++mm)
#pragma unroll
        for (int ks = 0; ks < 2; ++ks)
          af[mm][ks] = *(const f16x8*)&As[slot][(wm * 128 + (2 * q + mm) * 16 + lr) * 64 +
                                               (((ks << 2) + lg) ^ swr) * 8];
      __builtin_amdgcn_s_setprio(1);
#pragma unroll
      for (int mm = 0; mm < 2; ++mm)
#pragma unroll
        for (int nf = 0; nf < 4; ++nf)
#pragma unroll
          for (int ks = 0; ks < 2; ++ks)
            acc[2 * q + mm][nf] = MFMA_F16(af[mm][ks], bf[nf][ks], acc[2 * q + mm][nf]);
      __builtin_amdgcn_s_setprio(0);
    }
  }
#undef STAGE_A
#undef STAGE_B

  if (MODE == 0) {
#pragma unroll
    for (int nf = 0; nf < 4; ++nf) {
      int col = n0 + wn * 64 + nf * 16 + lr;
      int which = col >> 10;            // wave-uniform: 0:q 1:k 2:v (tile within segment)
      int rem = col & 1023;
      int h = rem >> 6, d = rem & 63;
      int fi = d >> 1;
      float sc = (which == 0) ? QSCALE : 1.0f;
#pragma unroll
      for (int mf = 0; mf < 8; ++mf) {
        int row0 = m0 + wm * 128 + mf * 16 + lg * 4;
        int bbo = row0 >> 12;           // constant over the 4-row quad
        int n = row0 & 4095;
        if (which == 2) {
          // VT[bh][dv][tok]: 4 consecutive tok -> packed uint2
          uint2 yw;
          yw.x = pkh2(acc[mf][nf][0], acc[mf][nf][1]);
          yw.y = pkh2(acc[mf][nf][2], acc[mf][nf][3]);
          *(uint2*)&vtd[((size_t)(bbo * NH + h) * HD + d) * NTOK + n] = yw;
        } else {
#pragma unroll
          for (int r = 0; r < 4; ++r) {
            float val = acc[mf][nf][r];
            float par = __shfl_xor(val, 1);
            float cc = ct[(n + r) * 32 + fi], ss = st[(n + r) * 32 + fi];
            float a0 = val * sc, a1 = par * sc;
            float o = (d & 1) ? fmaf(a0, cc, a1 * ss) : fmaf(a0, cc, -(a1 * ss));
            size_t idx = ((size_t)(bbo * NH + h) * NTOK + n + r) * HD + d;
            ((which == 0) ? qd : kd)[idx] = (u16)f2bf(o);
          }
        }
      }
    }
  } else {
#pragma unroll
    for (int nf = 0; nf < 4; ++nf) {
      int col = n0 + wn * 64 + nf * 16 + lr;
      float bl_ = bias[col];
#pragma unroll
      for (int mf = 0; mf < 8; ++mf) {
        int row0 = m0 + wm * 128 + mf * 16 + lg * 4;
#pragma unroll
        for (int r = 0; r < 4; ++r)
          C[(size_t)(row0 + r) * 1024 + col] = acc[mf][nf][r] + bl_;
      }
    }
  }
}

// ---------------- MFMA block attention, swapped-operand orientation (unchanged) ----------------
#define KP 72   // K LDS pitch (bf16)
#define VP 136  // V^T LDS pitch (fp16)
#define PP 136  // P LDS pitch (fp16)
template <int LV, int FINE>
__global__ __launch_bounds__(256, 2) void attn_mfma_kernel(
    const u16* __restrict__ qg, const u16* __restrict__ kgl, const u16* __restrict__ vtg,
    u16* __restrict__ yl, float* __restrict__ al) {
  constexpr int R = 1 << LV;
  constexpr float QKSC = 1.0f / (float)R;
  __shared__ __align__(16) u16 Ks[128 * KP];
  __shared__ __align__(16) u16 Vt[64 * VP];
  __shared__ __align__(16) u16 Ps[128 * PP];
  const int t = threadIdx.x;
  const int blk = blockIdx.x, bh = blockIdx.y;
  const int l = t & 63, w = t >> 6;
  const int lr = l & 15, lg = l >> 4;
  const int nl = NTOK >> LV;
  const size_t bbase = (size_t)bh * NTOK;

  s16x8 aq[2][2];
#pragma unroll
  for (int qf = 0; qf < 2; ++qf)
#pragma unroll
    for (int ks = 0; ks < 2; ++ks) {
      int qrow = blk * 128 + w * 32 + qf * 16 + lr;
      const u16* src = qg + (bbase + ((size_t)qrow << LV)) * HD + ks * 32 + lg * 8;
      if (LV == 0) {
        aq[qf][ks] = *(const s16x8*)src;
      } else {
        float s[8] = {};
#pragma unroll
        for (int ss = 0; ss < R; ++ss) {
          uint4 a = *(const uint4*)(src + (size_t)ss * HD);
          float f[8];
          up8(a, f);
#pragma unroll
          for (int c = 0; c < 8; ++c) s[c] += f[c];
        }
        union { uint4 u; s16x8 v; } cv;
        cv.u = make_uint4(pk2(s[0] * QKSC, s[1] * QKSC), pk2(s[2] * QKSC, s[3] * QKSC),
                          pk2(s[4] * QKSC, s[5] * QKSC), pk2(s[6] * QKSC, s[7] * QKSC));
        aq[qf][ks] = cv.v;
      }
    }

  f32x4 zero4 = {0.f, 0.f, 0.f, 0.f};
  f32x4 accYT[4][2];  // [dvf][qf]; lane: q = qf*16+lr, dv = dvf*16+lg*4+r
  float asum[2] = {0.f, 0.f};
#pragma unroll
  for (int dvf = 0; dvf < 4; ++dvf)
#pragma unroll
    for (int qf = 0; qf < 2; ++qf) accYT[dvf][qf] = zero4;

  const int npass = FINE ? 2 : 1;
  for (int pass = 0; pass < npass; ++pass) {
    const int kblk = (pass == 0) ? (blk ^ 1) : blk;
    __syncthreads();  // prev pass's LDS readers done
#pragma unroll
    for (int it = 0; it < 2; ++it) {
      int kk = it * 64 + (t >> 2), dq = (t & 3) * 16;
      const u16* src = kgl + (bbase + (((size_t)kblk * 128 + kk) << LV)) * HD + dq;
      if (LV == 0) {
        *(uint4*)&Ks[kk * KP + dq] = *(const uint4*)src;
        *(uint4*)&Ks[kk * KP + dq + 8] = *(const uint4*)(src + 8);
      } else {
        float s[16] = {};
#pragma unroll
        for (int ss = 0; ss < R; ++ss) {
          float f[8];
          up8(*(const uint4*)(src + (size_t)ss * HD), f);
#pragma unroll
          for (int c = 0; c < 8; ++c) s[c] += f[c];
          up8(*(const uint4*)(src + (size_t)ss * HD + 8), f);
#pragma unroll
          for (int c = 0; c < 8; ++c) s[8 + c] += f[c];
        }
        u32 pk[8];
#pragma unroll
        for (int j = 0; j < 8; ++j) pk[j] = pk2(s[2 * j] * QKSC, s[2 * j + 1] * QKSC);
        *(uint4*)&Ks[kk * KP + dq] = make_uint4(pk[0], pk[1], pk[2], pk[3]);
        *(uint4*)&Ks[kk * KP + dq + 8] = make_uint4(pk[4], pk[5], pk[6], pk[7]);
      }
    }
    {
      int dv = t >> 2, j0 = (t & 3) * 32;
      const u16* src = vtg + ((size_t)bh * HD + dv) * NTOK +
                       (((size_t)(kblk * 128 + j0)) << LV);
      if (LV == 0) {
#pragma unroll
        for (int c = 0; c < 4; ++c)
          *(uint4*)&Vt[dv * VP + j0 + c * 8] = *(const uint4*)(src + c * 8);
      } else {
        float acc[32];
#pragma unroll
        for (int j = 0; j < 32; ++j) acc[j] = 0.f;
#pragma unroll
        for (int c = 0; c < 4 * R; ++c) {
          float f[8];
          up8h(*(const uint4*)(src + c * 8), f);
#pragma unroll
          for (int e = 0; e < 8; ++e) acc[(c * 8 + e) >> LV] += f[e];
        }
#pragma unroll
        for (int j = 0; j < 32; j += 8) {
          uint4 pkv;
          pkv.x = pkh2(acc[j + 0], acc[j + 1]);
          pkv.y = pkh2(acc[j + 2], acc[j + 3]);
          pkv.z = pkh2(acc[j + 4], acc[j + 5]);
          pkv.w = pkh2(acc[j + 6], acc[j + 7]);
          *(uint4*)&Vt[dv * VP + j0 + j] = pkv;
        }
      }
    }
    __syncthreads();
    f32x4 accST[8][2];
#pragma unroll
    for (int kf = 0; kf < 8; ++kf)
#pragma unroll
      for (int qf = 0; qf < 2; ++qf) accST[kf][qf] = zero4;
#pragma unroll
    for (int kf = 0; kf < 8; ++kf)
#pragma unroll
      for (int ks = 0; ks < 2; ++ks) {
        s16x8 ak = *(const s16x8*)&Ks[(kf * 16 + lr) * KP + ks * 32 + lg * 8];
        accST[kf][0] = MFMA_BF16(ak, aq[0][ks], accST[kf][0]);
        accST[kf][1] = MFMA_BF16(ak, aq[1][ks], accST[kf][1]);
      }
#pragma unroll
    for (int qf = 0; qf < 2; ++qf) {
      float m = accST[0][qf][0];
#pragma unroll
      for (int kf = 0; kf < 8; ++kf)
#pragma unroll
        for (int r = 0; r < 4; ++r) m = fmaxf(m, accST[kf][qf][r]);
      m = fmaxf(m, __shfl_xor(m, 16));
      m = fmaxf(m, __shfl_xor(m, 32));
      float s = 0.f;
#pragma unroll
      for (int kf = 0; kf < 8; ++kf) {
#pragma unroll
        for (int r = 0; r < 4; ++r) {
          float e = __expf(accST[kf][qf][r] - m);
          accST[kf][qf][r] = e;
          s += e;
        }
      }
      s += __shfl_xor(s, 16);
      s += __shfl_xor(s, 32);
      asum[qf] += s;
#pragma unroll
      for (int kf = 0; kf < 8; ++kf) {
        uint2 pw;
        pw.x = pkh2(accST[kf][qf][0], accST[kf][qf][1]);
        pw.y = pkh2(accST[kf][qf][2], accST[kf][qf][3]);
        *(uint2*)&Ps[(w * 32 + qf * 16 + lr) * PP + kf * 16 + lg * 4] = pw;
      }
    }
#pragma unroll
    for (int ks4 = 0; ks4 < 4; ++ks4) {
      f16x8 pf[2];
#pragma unroll
      for (int qf = 0; qf < 2; ++qf)
        pf[qf] = *(const f16x8*)&Ps[(w * 32 + qf * 16 + lr) * PP + ks4 * 32 + lg * 8];
#pragma unroll
      for (int dvf = 0; dvf < 4; ++dvf) {
        f16x8 vf = *(const f16x8*)&Vt[(dvf * 16 + lr) * VP + ks4 * 32 + lg * 8];
        accYT[dvf][0] = MFMA_F16(vf, pf[0], accYT[dvf][0]);
        accYT[dvf][1] = MFMA_F16(vf, pf[1], accYT[dvf][1]);
      }
    }
  }
#pragma unroll
  for (int qf = 0; qf < 2; ++qf) {
    if (lg == 0)
      al[(size_t)bh * nl + blk * 128 + w * 32 + qf * 16 + lr] = asum[qf];
    int q = blk * 128 + w * 32 + qf * 16 + lr;
#pragma unroll
    for (int dvf = 0; dvf < 4; ++dvf) {
      uint2 yw;
      yw.x = pkh2(accYT[dvf][qf][0], accYT[dvf][qf][1]);
      yw.y = pkh2(accYT[dvf][qf][2], accYT[dvf][qf][3]);
      *(uint2*)&yl[((size_t)bh * nl + q) * HD + dvf * 16 + lg * 4] = yw;
    }
  }
}

// ---------------- pyramid combine (fp16 Y inputs) ----------------
__global__ __launch_bounds__(256) void combine_pyr_kernel(
    const u16* __restrict__ Yf, const u16* __restrict__ Y1, const u16* __restrict__ Y2,
    const u16* __restrict__ Y3, const u16* __restrict__ Y4,
    const float* __restrict__ Af, const float* __restrict__ A1, const float* __restrict__ A2,
    const float* __restrict__ A3, const float* __restrict__ A4, u16* __restrict__ out) {
  int row = blockIdx.x, t = threadIdx.x;  // row = b*4096 + tok
  int b = row >> 12, tok = row & 4095;
  int h = t >> 4, d = (t & 15) * 4;
  int bh = b * NH + h;
  float a = Af[(size_t)bh * 4096 + tok] + A1[(size_t)bh * 2048 + (tok >> 1)] +
            A2[(size_t)bh * 1024 + (tok >> 2)] + A3[(size_t)bh * 512 + (tok >> 3)] +
            A4[(size_t)bh * 256 + (tok >> 4)] + 1e-8f;
  float y[4] = {0.f, 0.f, 0.f, 0.f}, f[4];
  up4h(*(const uint2*)&Yf[((size_t)bh * 4096 + tok) * HD + d], f);
#pragma unroll
  for (int c = 0; c < 4; ++c) y[c] += f[c];
  up4h(*(const uint2*)&Y1[((size_t)bh * 2048 + (tok >> 1)) * HD + d], f);
#pragma unroll
  for (int c = 0; c < 4; ++c) y[c] += f[c];
  up4h(*(const uint2*)&Y2[((size_t)bh * 1024 + (tok >> 2)) * HD + d], f);
#pragma unroll
  for (int c = 0; c < 4; ++c) y[c] += f[c];
  up4h(*(const uint2*)&Y3[((size_t)bh * 512 + (tok >> 3)) * HD + d], f);
#pragma unroll
  for (int c = 0; c < 4; ++c) y[c] += f[c];
  up4h(*(const uint2*)&Y4[((size_t)bh * 256 + (tok >> 4)) * HD + d], f);
#pragma unroll
  for (int c = 0; c < 4; ++c) y[c] += f[c];
  float inv = 1.0f / a;
  *(uint2*)&out[(size_t)row * HID + t * 4] =
      make_uint2(pkh2(y[0] * inv, y[1] * inv), pkh2(y[2] * inv, y[3] * inv));
}

extern "C" void kernel_launch(void* const* d_in, const int* in_sizes, int n_in,
                              void* d_out, int out_size, void* d_ws, size_t ws_size,
                              hipStream_t stream) {
  (void)in_sizes; (void)n_in;
  const float* hs = (const float*)d_in[0];
  const float* gm = (const float*)d_in[1];
  const float* bt = (const float*)d_in[2];
  const float* wqkv = (const float*)d_in[3];
  const float* wout = (const float*)d_in[4];
  const float* bout = (const float*)d_in[5];
  float* out = (float*)d_out;

  const size_t MB = 1024ull * 1024ull;
  unsigned char* base = (unsigned char*)d_ws;
  const size_t need = 233 * MB;
  if (ws_size < need) {  // diagnostic: absmax will read ~ (1000 + ws_MiB)
    fill_kernel<<<(out_size + 255) / 256, 256, 0, stream>>>(out, out_size,
                                                            1000.0f + (float)(ws_size >> 20));
    return;
  }

  u16* Qf = (u16*)(base);                    // 32 MiB bf16 [BH][4096][64]
  u16* Kf = (u16*)(base + 32 * MB);          // 32 MiB bf16
  u16* VT = (u16*)(base + 64 * MB);          // 32 MiB fp16 [bh][dv][tok] (written by gemm)
  u16* Yf = (u16*)(base + 96 * MB);          // 32 MiB fp16 fine Y
  u16* Y1 = (u16*)(base + 160 * MB);         // 16 MiB
  u16* Y2 = (u16*)(base + 176 * MB);         // 8 MiB
  u16* Y3 = (u16*)(base + 184 * MB);         // 4 MiB
  u16* Y4 = (u16*)(base + 188 * MB);         // 2 MiB
  float* AACC = (float*)(base + 190 * MB);   // ~2 MiB A pyramid (f32)
  float* A1 = AACC + (size_t)BH * 4096;
  float* A2 = A1 + (size_t)BH * 2048;
  float* A3 = A2 + (size_t)BH * 1024;
  float* A4 = A3 + (size_t)BH * 512;
  u16* WQT = (u16*)(base + 192 * MB);        // 6 MiB fp16 [3072][1024]
  u16* WOT = (u16*)(base + 198 * MB);        // 2 MiB fp16 [1024][1024]
  float* CT = (float*)(base + 200 * MB);     // 512 KiB
  float* ST = CT + NTOK * 32;                // 512 KiB
  u16* ALN = (u16*)(base + 201 * MB);        // 32 MiB fp16 [16384][1024]
  u16* ATT = (u16*)(base);                   // overlays Qf (dead after attn)

  rope_table_kernel<<<(NTOK * 32 + 255) / 256, 256, 0, stream>>>(CT, ST);
  ln_f16_kernel<<<NB * NTOK, 256, 0, stream>>>(hs, gm, bt, ALN);
  prep_w_kernel<<<dim3(48, 16), 256, 0, stream>>>(wqkv, WQT, 3072);
  prep_w_kernel<<<dim3(16, 16), 256, 0, stream>>>(wout, WOT, 1024);

  // qkv: M=16384 N=3072 -> 64 x 12 = 768 WGs (%8==0)
  gemm256_kernel<0><<<768, 512, 0, stream>>>(
      ALN, WQT, Qf, Kf, VT, CT, ST, nullptr, nullptr, 12);

  attn_mfma_kernel<0, 1><<<dim3(32, BH), 256, 0, stream>>>(Qf, Kf, VT, Yf, AACC);
  attn_mfma_kernel<1, 0><<<dim3(16, BH), 256, 0, stream>>>(Qf, Kf, VT, Y1, A1);
  attn_mfma_kernel<2, 0><<<dim3(8, BH), 256, 0, stream>>>(Qf, Kf, VT, Y2, A2);
  attn_mfma_kernel<3, 0><<<dim3(4, BH), 256, 0, stream>>>(Qf, Kf, VT, Y3, A3);
  attn_mfma_kernel<4, 0><<<dim3(2, BH), 256, 0, stream>>>(Qf, Kf, VT, Y4, A4);

  combine_pyr_kernel<<<NB * NTOK, 256, 0, stream>>>(Yf, Y1, Y2, Y3, Y4,
                                                    AACC, A1, A2, A3, A4, ATT);
  // out: M=16384 N=1024 -> 64 x 4 = 256 WGs (%8==0)
  gemm256_kernel<1><<<256, 512, 0, stream>>>(
      ATT, WOT, nullptr, nullptr, nullptr, nullptr, nullptr, bout, out, 4);
}